// Round 7
// baseline (197.638 us; speedup 1.0000x reference)
//
#include <hip/hip_runtime.h>
#include <math.h>

#define N_ENT 50000
#define N_REL 500
#define DEG 32
#define TOPK 10
#define H_DIM 256
#define N_HEADS 4
#define HEAD_DIM 64

typedef __attribute__((ext_vector_type(8))) short short8v;
typedef __attribute__((ext_vector_type(4))) float f32x4;

// ---------------- workspace layout (bytes) ----------------
constexpr size_t OFF_SSRC0 = 0;                      // f64 [N_ENT]
constexpr size_t OFF_SR0   = 400000;                 // f64 [N_REL]
constexpr size_t OFF_U0    = 404000;                 // f64 [256]
constexpr size_t OFF_V0    = 406048;                 // f64 [256]
constexpr size_t OFF_SS    = 408096;                 // f32 [N_ENT][8]
constexpr size_t OFF_SSR   = 2008096;                // f32 [N_REL][8] (cols 0..3 = sr4)
constexpr size_t OFF_U8    = 2024096;                // f32 [256][8]
constexpr size_t OFF_V8    = 2032288;                // f32 [256][8]
constexpr size_t OFF_B1H   = 2040480;                // bf16 packed 131072 B each
constexpr size_t OFF_B1L   = 2171552;
constexpr size_t OFF_B2H   = 2302624;
constexpr size_t OFF_B2L   = 2433696;
constexpr size_t OFF_B3H   = 2564768;
constexpr size_t OFF_B3L   = 2695840;
constexpr size_t OFF_RPK   = 2826912;                // bf16 packed rel rows (512) 262144 B
constexpr size_t OFF_EAH   = 3089056;                // bf16 packed A (ent; later neigh) 25,624,576 B
constexpr size_t OFF_EMBBF = 28713632;               // bf16 [N_ENT][256] emb_t (row-major)
constexpr size_t OFF_RELBF = 54313632;               // bf16 [N_REL][256]
constexpr size_t OFF_IDX   = 54569632;               // u32 [N_ENT][10]
constexpr size_t OFF_WQ    = 56569632;               // f32 [N_ENT][4][10]
constexpr size_t WS_NEED   = 64569632;               // ~62 MB

__device__ __forceinline__ float leaky(float x) { return x >= 0.f ? x : 0.2f * x; }

__device__ __forceinline__ unsigned short bf16_rne(float x) {
    unsigned int u = __float_as_uint(x);
    unsigned int r = u + 0x7fffu + ((u >> 16) & 1u);
    return (unsigned short)(r >> 16);
}
__device__ __forceinline__ float bf2f(unsigned short x) {
    return __uint_as_float((unsigned)x << 16);
}

// MFMA-fragment pack offset for element (row, d) of a [R][256] bf16 matrix.
__device__ __forceinline__ size_t pack_off(int row, int d) {
    return ((size_t)(row >> 4) * 8 + (d >> 5)) * 512 +
           (((d >> 3) & 3) * 16 + (row & 15)) * 8 + (d & 7);
}

// ---------------- K0: setup (U/V vectors | B splits) — all tiny parallel work ----------------
__global__ __launch_bounds__(256) void setup_kernel(
    const float* __restrict__ W, const float* __restrict__ W_r,
    const float* __restrict__ a, const float* __restrict__ nw,
    float* __restrict__ U8, double* __restrict__ u0,
    float* __restrict__ V8, double* __restrict__ v0,
    unsigned short* __restrict__ b1h, unsigned short* __restrict__ b1l,
    unsigned short* __restrict__ b2h, unsigned short* __restrict__ b2l,
    unsigned short* __restrict__ b3h, unsigned short* __restrict__ b3l)
{
    const int bid = blockIdx.x;
    const int tid = threadIdx.x;
    if (bid == 0) {
        // entity score vectors: U8[d][h]=W[h][d]·a_src, U8[d][4+h]=W[h][d]·a_dst, u0 f64
        int d = tid;
        #pragma unroll
        for (int h = 0; h < N_HEADS; ++h) {
            float ss = 0.f, sd = 0.f;
            #pragma unroll
            for (int e = 0; e < HEAD_DIM; ++e) {
                float w = W[h * 16384 + d * 64 + e];
                ss += w * a[h * 192 + e];
                sd += w * a[h * 192 + 64 + e];
            }
            U8[d * 8 + h] = ss;
            U8[d * 8 + 4 + h] = sd;
        }
        double s0 = 0.0;
        #pragma unroll
        for (int e = 0; e < HEAD_DIM; ++e)
            s0 += (double)W[d * 64 + e] * (double)a[e];
        u0[d] = s0;
    } else if (bid == 1) {
        // relation score vectors: V8[d][h]=W_r[h][d]·a_rel(h), v0 f64 (head 0)
        int d = tid;
        #pragma unroll
        for (int h = 0; h < N_HEADS; ++h) {
            float sv = 0.f;
            #pragma unroll
            for (int e = 0; e < HEAD_DIM; ++e)
                sv += W_r[h * 16384 + d * 64 + e] * a[h * 192 + 128 + e];
            V8[d * 8 + h] = sv;
            V8[d * 8 + 4 + h] = 0.f;
        }
        double s0 = 0.0;
        #pragma unroll
        for (int e = 0; e < HEAD_DIM; ++e)
            s0 += (double)W_r[d * 64 + e] * (double)a[128 + e];
        v0[d] = s0;
    } else {
        // B splits for col n into packed fragment layout
        int n = bid - 2;     // output col
        int k = tid;         // inner dim
        int h = n >> 6, e = n & 63;
        float x1 = W[h * 16384 + k * 64 + e];
        float x2 = nw[k * 256 + n];
        float x3 = W_r[h * 16384 + k * 64 + e];
        size_t off = pack_off(n, k);
        unsigned short h1 = bf16_rne(x1);
        b1h[off] = h1; b1l[off] = bf16_rne(x1 - bf2f(h1));
        unsigned short h2 = bf16_rne(x2);
        b2h[off] = h2; b2l[off] = bf16_rne(x2 - bf2f(h2));
        unsigned short h3 = bf16_rne(x3);
        b3h[off] = h3; b3l[off] = bf16_rne(x3 - bf2f(h3));
    }
}

// ---------------- K3: rank-1 scores + packed bf16 split (entities AND relations) ----------------
// SSout[n][0..7] = X[n]·U8[:,0..7] (f32), s0out[n] = X[n]·u0 (f64), Xpk = packed bf16-hi of X
__global__ __launch_bounds__(256) void ss_kernel(
    const float* __restrict__ X, const float* __restrict__ U8v,
    const double* __restrict__ u0v,
    float* __restrict__ SSout, double* __restrict__ s0out,
    unsigned short* __restrict__ Xpk, int N)
{
    const int tid = threadIdx.x;
    const int l = tid & 63;
    const int el = l & 31;
    const int q2 = l >> 5;

    float uu[8][8];
    #pragma unroll
    for (int i = 0; i < 8; ++i) {
        float4 a4 = *(const float4*)(U8v + (el * 8 + i) * 8);
        float4 b4 = *(const float4*)(U8v + (el * 8 + i) * 8 + 4);
        uu[i][0] = a4.x; uu[i][1] = a4.y; uu[i][2] = a4.z; uu[i][3] = a4.w;
        uu[i][4] = b4.x; uu[i][5] = b4.y; uu[i][6] = b4.z; uu[i][7] = b4.w;
    }
    double ud[8];
    #pragma unroll
    for (int i = 0; i < 8; ++i) ud[i] = u0v[el * 8 + i];

    int wave = (blockIdx.x * 256 + tid) >> 6;
    int nwaves = gridDim.x * 4;
    for (int p = wave; p < N / 2; p += nwaves) {
        int n = p * 2 + q2;
        float4 x1 = *(const float4*)(X + (size_t)n * 256 + el * 8);
        float4 x2 = *(const float4*)(X + (size_t)n * 256 + el * 8 + 4);
        float xs[8] = {x1.x, x1.y, x1.z, x1.w, x2.x, x2.y, x2.z, x2.w};

        short8v ov;
        #pragma unroll
        for (int i = 0; i < 8; ++i) ov[i] = (short)bf16_rne(xs[i]);
        *(short8v*)(Xpk + pack_off(n, el * 8)) = ov;

        float pj[8] = {0.f, 0.f, 0.f, 0.f, 0.f, 0.f, 0.f, 0.f};
        double pd = 0.0;
        #pragma unroll
        for (int i = 0; i < 8; ++i) {
            #pragma unroll
            for (int j = 0; j < 8; ++j) pj[j] += xs[i] * uu[i][j];
            pd += (double)xs[i] * ud[i];
        }
        #pragma unroll
        for (int off = 1; off < 32; off <<= 1) {
            #pragma unroll
            for (int j = 0; j < 8; ++j) pj[j] += __shfl_xor(pj[j], off);
            pd += __shfl_xor(pd, off);
        }
        if (el == 0) {
            float4 o1; o1.x = pj[0]; o1.y = pj[1]; o1.z = pj[2]; o1.w = pj[3];
            float4 o2; o2.x = pj[4]; o2.y = pj[5]; o2.z = pj[6]; o2.w = pj[7];
            *(float4*)(SSout + (size_t)n * 8) = o1;
            *(float4*)(SSout + (size_t)n * 8 + 4) = o2;
            s0out[n] = pd;
        }
    }
}

// ---------------- K4/K6: packed-fragment MFMA GEMM, no LDS, no barriers ----------------
// mode: 1 = bf16 out (row-major), 2 = f32 + tanh
__global__ __launch_bounds__(256, 4) void gemm_pk(
    const unsigned short* __restrict__ Apk,
    const unsigned short* __restrict__ Bpkh, const unsigned short* __restrict__ Bpkl,
    void* __restrict__ Cout, int M, int mode)
{
    const int tid = threadIdx.x;
    const int l = tid & 63;
    const int w = tid >> 6;
    const int bm = blockIdx.x * 64;
    const int rl = l & 15;
    const int ql = l >> 4;

    const unsigned short* ab = Apk + (size_t)(bm >> 4) * 4096 + l * 8;
    const unsigned short* bhb = Bpkh + (size_t)w * 16384 + l * 8;
    const unsigned short* blb = Bpkl + (size_t)w * 16384 + l * 8;

    f32x4 acc[4][4];
    #pragma unroll
    for (int i = 0; i < 4; ++i)
        #pragma unroll
        for (int j = 0; j < 4; ++j) acc[i][j] = (f32x4){0.f, 0.f, 0.f, 0.f};

    #pragma unroll 2
    for (int ks = 0; ks < 8; ++ks) {
        short8v ah[4], bh[4], bl[4];
        #pragma unroll
        for (int mf = 0; mf < 4; ++mf)
            ah[mf] = *(const short8v*)(ab + mf * 4096 + ks * 512);
        #pragma unroll
        for (int nf = 0; nf < 4; ++nf) {
            bh[nf] = *(const short8v*)(bhb + nf * 4096 + ks * 512);
            bl[nf] = *(const short8v*)(blb + nf * 4096 + ks * 512);
        }
        #pragma unroll
        for (int mf = 0; mf < 4; ++mf)
            #pragma unroll
            for (int nf = 0; nf < 4; ++nf) {
                acc[mf][nf] = __builtin_amdgcn_mfma_f32_16x16x32_bf16(ah[mf], bh[nf], acc[mf][nf], 0, 0, 0);
                acc[mf][nf] = __builtin_amdgcn_mfma_f32_16x16x32_bf16(ah[mf], bl[nf], acc[mf][nf], 0, 0, 0);
            }
    }

    // epilogue: D col = lane&15, row = (lane>>4)*4 + reg
    #pragma unroll
    for (int mf = 0; mf < 4; ++mf) {
        int row0 = bm + mf * 16 + ql * 4;
        #pragma unroll
        for (int nf = 0; nf < 4; ++nf) {
            int c = w * 64 + nf * 16 + rl;
            #pragma unroll
            for (int j = 0; j < 4; ++j) {
                int r = row0 + j;
                if (r < M) {
                    float v = acc[mf][nf][j];
                    if (mode == 2)
                        ((float*)Cout)[(size_t)r * 256 + c] =
                            1.f - 2.f / (__expf(2.f * v) + 1.f);
                    else
                        ((unsigned short*)Cout)[(size_t)r * 256 + c] = bf16_rne(v);
                }
            }
        }
    }
}

// ---------------- K5a: top-k select + softmax weights ----------------
// 32 lanes per node, 8 nodes per block
__global__ __launch_bounds__(256) void select_kernel(
    const int* __restrict__ src, const int* __restrict__ relid,
    const float* __restrict__ SS, const double* __restrict__ ssrc0,
    const float* __restrict__ SSR, const double* __restrict__ sr0,
    unsigned* __restrict__ idxp, float* __restrict__ wq)
{
    __shared__ __align__(16) float sr4s[N_REL * 4];
    __shared__ double sr0s[N_REL];
    for (int i = threadIdx.x; i < N_REL; i += 256) {
        *(float4*)&sr4s[i * 4] = *(const float4*)&SSR[i * 8];
        sr0s[i] = sr0[i];
    }
    __syncthreads();

    const int tid = threadIdx.x;
    const int l = tid & 63;
    const int el = l & 31;
    const int hb = l & 32;
    const int n = blockIdx.x * 8 + (tid >> 5);

    const int sd_ = src[n * DEG + el];
    const int rd_ = relid[n * DEG + el];
    const double sc0 = ssrc0[sd_] + sr0s[rd_];

    // rank by count (stable: lower index wins ties)
    int cnt = 0;
    #pragma unroll
    for (int j = 0; j < DEG; ++j) {
        double sj = __shfl(sc0, hb | j);
        cnt += (sj > sc0 || (sj == sc0 && j < el)) ? 1 : 0;
    }
    const bool sel = (cnt < TOPK);
    const unsigned mask = (unsigned)(__ballot(sel) >> hb);

    float scx = -1e30f, scy = -1e30f, scz = -1e30f, scw = -1e30f;
    if (sel) {
        float4 ssv = *(const float4*)(SS + (size_t)sd_ * 8);
        float4 srv = *(const float4*)&sr4s[rd_ * 4];
        float4 sdv = *(const float4*)(SS + (size_t)n * 8 + 4);
        scx = leaky(ssv.x + sdv.x + srv.x);
        scy = leaky(ssv.y + sdv.y + srv.y);
        scz = leaky(ssv.z + sdv.z + srv.z);
        scw = leaky(ssv.w + sdv.w + srv.w);
    }

    float mx = scx, my = scy, mz = scz, mw = scw;
    #pragma unroll
    for (int off = 1; off < 32; off <<= 1) {
        mx = fmaxf(mx, __shfl_xor(mx, off));
        my = fmaxf(my, __shfl_xor(my, off));
        mz = fmaxf(mz, __shfl_xor(mz, off));
        mw = fmaxf(mw, __shfl_xor(mw, off));
    }
    float ex = sel ? __expf(scx - mx) : 0.f;
    float ey = sel ? __expf(scy - my) : 0.f;
    float ez = sel ? __expf(scz - mz) : 0.f;
    float ew = sel ? __expf(scw - mw) : 0.f;
    float sx = ex, sy = ey, sz = ez, sw = ew;
    #pragma unroll
    for (int off = 1; off < 32; off <<= 1) {
        sx += __shfl_xor(sx, off);
        sy += __shfl_xor(sy, off);
        sz += __shfl_xor(sz, off);
        sw += __shfl_xor(sw, off);
    }

    if (sel) {
        int pos = __popc(mask & ((1u << el) - 1u));
        idxp[n * TOPK + pos] = (unsigned)sd_ | ((unsigned)rd_ << 16);
        float* wqn = wq + (size_t)n * 40;
        wqn[0 * TOPK + pos] = ex / sx;
        wqn[1 * TOPK + pos] = ey / sy;
        wqn[2 * TOPK + pos] = ez / sz;
        wqn[3 * TOPK + pos] = ew / sw;
    }
}

// ---------------- K5b: gather-aggregate (pure memory kernel) ----------------
// 32 lanes per node (8 dims/lane), 8 nodes per block; packed output
__global__ __launch_bounds__(256) void aggr_kernel(
    const unsigned* __restrict__ idxp, const float* __restrict__ wq,
    const unsigned short* __restrict__ emb_bf, const unsigned short* __restrict__ rel_bf,
    unsigned short* __restrict__ napk)
{
    const int tid = threadIdx.x;
    const int el = tid & 31;
    const int n = blockIdx.x * 8 + (tid >> 5);
    const int h = el >> 3;

    unsigned id[TOPK];
    float wgt[TOPK];
    const unsigned* ip = idxp + (size_t)n * TOPK;
    const float* wp = wq + (size_t)n * 40 + h * TOPK;
    #pragma unroll
    for (int k = 0; k < TOPK; ++k) id[k] = ip[k];
    #pragma unroll
    for (int k = 0; k < TOPK; ++k) wgt[k] = wp[k];

    float acc[8] = {0.f, 0.f, 0.f, 0.f, 0.f, 0.f, 0.f, 0.f};
    #pragma unroll
    for (int k = 0; k < TOPK; ++k) {
        int sk = id[k] & 0xFFFF;
        int rk = id[k] >> 16;
        short8v ev = *(const short8v*)(emb_bf + (size_t)sk * 256 + el * 8);
        short8v rv = *(const short8v*)(rel_bf + (size_t)rk * 256 + el * 8);
        float w = wgt[k];
        #pragma unroll
        for (int j = 0; j < 8; ++j)
            acc[j] += w * (bf2f((unsigned short)ev[j]) + bf2f((unsigned short)rv[j]));
    }

    short8v ov;
    #pragma unroll
    for (int j = 0; j < 8; ++j) ov[j] = (short)bf16_rne(acc[j]);
    *(short8v*)(napk + pack_off(n, el * 8)) = ov;
}

extern "C" void kernel_launch(void* const* d_in, const int* in_sizes, int n_in,
                              void* d_out, int out_size, void* d_ws, size_t ws_size,
                              hipStream_t stream) {
    const float* ent  = (const float*)d_in[0];
    const float* rel  = (const float*)d_in[1];
    const float* W    = (const float*)d_in[2];
    const float* W_r  = (const float*)d_in[3];
    const float* a    = (const float*)d_in[4];
    const float* nw   = (const float*)d_in[5];
    const int*   srcp = (const int*)d_in[6];
    const int*   ridp = (const int*)d_in[7];
    float* out = (float*)d_out;

    if (ws_size < WS_NEED) return;

    char* ws = (char*)d_ws;
    double* ssrc0 = (double*)(ws + OFF_SSRC0);
    double* sr0   = (double*)(ws + OFF_SR0);
    double* u0    = (double*)(ws + OFF_U0);
    double* v0    = (double*)(ws + OFF_V0);
    float*  SS    = (float*)(ws + OFF_SS);
    float*  SSR   = (float*)(ws + OFF_SSR);
    float*  U8    = (float*)(ws + OFF_U8);
    float*  V8    = (float*)(ws + OFF_V8);
    unsigned short* b1h = (unsigned short*)(ws + OFF_B1H);
    unsigned short* b1l = (unsigned short*)(ws + OFF_B1L);
    unsigned short* b2h = (unsigned short*)(ws + OFF_B2H);
    unsigned short* b2l = (unsigned short*)(ws + OFF_B2L);
    unsigned short* b3h = (unsigned short*)(ws + OFF_B3H);
    unsigned short* b3l = (unsigned short*)(ws + OFF_B3L);
    unsigned short* rpk = (unsigned short*)(ws + OFF_RPK);
    unsigned short* apk = (unsigned short*)(ws + OFF_EAH);
    unsigned short* embbf = (unsigned short*)(ws + OFF_EMBBF);
    unsigned short* relbf = (unsigned short*)(ws + OFF_RELBF);
    unsigned* idxp = (unsigned*)(ws + OFF_IDX);
    float*    wqp  = (float*)(ws + OFF_WQ);
    // neigh-packed aliases ent-packed (dead after gemm1)
    unsigned short* napk = apk;

    setup_kernel<<<258, 256, 0, stream>>>(W, W_r, a, nw, U8, u0, V8, v0,
                                          b1h, b1l, b2h, b2l, b3h, b3l);
    ss_kernel<<<512, 256, 0, stream>>>(ent, U8, u0, SS, ssrc0, apk, N_ENT);
    ss_kernel<<<63, 256, 0, stream>>>(rel, V8, v0, SSR, sr0, rpk, N_REL);
    gemm_pk<<<782, 256, 0, stream>>>(apk, b1h, b1l, embbf, N_ENT, 1);
    gemm_pk<<<8, 256, 0, stream>>>(rpk, b3h, b3l, relbf, N_REL, 1);
    select_kernel<<<6250, 256, 0, stream>>>(srcp, ridp, SS, ssrc0, SSR, sr0, idxp, wqp);
    aggr_kernel<<<6250, 256, 0, stream>>>(idxp, wqp, embbf, relbf, napk);
    gemm_pk<<<782, 256, 0, stream>>>(napk, b2h, b2l, out, N_ENT, 2);
}

// Round 8
// 189.385 us; speedup vs baseline: 1.0436x; 1.0436x over previous
//
#include <hip/hip_runtime.h>
#include <math.h>

#define N_ENT 50000
#define N_REL 500
#define DEG 32
#define TOPK 10
#define H_DIM 256
#define N_HEADS 4
#define HEAD_DIM 64

typedef __attribute__((ext_vector_type(8))) short short8v;
typedef __attribute__((ext_vector_type(4))) float f32x4;

// ---------------- workspace layout (bytes) ----------------
constexpr size_t OFF_SSRC0 = 0;                      // f64 [N_ENT]
constexpr size_t OFF_SR0   = 400000;                 // f64 [N_REL]
constexpr size_t OFF_U0    = 404000;                 // f64 [256]
constexpr size_t OFF_V0    = 406048;                 // f64 [256]
constexpr size_t OFF_SS    = 408096;                 // f32 [N_ENT][8]
constexpr size_t OFF_SSR   = 2008096;                // f32 [N_REL][8] (cols 0..3 = sr4)
constexpr size_t OFF_U8    = 2024096;                // f32 [256][8]
constexpr size_t OFF_V8    = 2032288;                // f32 [256][8]
constexpr size_t OFF_B1H   = 2040480;                // bf16 packed 131072 B each
constexpr size_t OFF_B1L   = 2171552;                // (unused now)
constexpr size_t OFF_B2H   = 2302624;
constexpr size_t OFF_B2L   = 2433696;
constexpr size_t OFF_B3H   = 2564768;
constexpr size_t OFF_B3L   = 2695840;                // (unused now)
constexpr size_t OFF_RPK   = 2826912;                // bf16 packed rel rows (512) 262144 B
constexpr size_t OFF_EAH   = 3089056;                // bf16 packed A (ent; later neigh) 25,624,576 B
constexpr size_t OFF_EMBBF = 28713632;               // bf16 [N_ENT][256] emb_t (row-major)
constexpr size_t OFF_RELBF = 54313632;               // bf16 [N_REL][256]
constexpr size_t OFF_IDX   = 54569632;               // u32 [N_ENT][10]
constexpr size_t OFF_WQ    = 56569632;               // f32 [N_ENT][4][10]
constexpr size_t WS_NEED   = 64569632;               // ~62 MB

__device__ __forceinline__ float leaky(float x) { return x >= 0.f ? x : 0.2f * x; }

__device__ __forceinline__ unsigned short bf16_rne(float x) {
    unsigned int u = __float_as_uint(x);
    unsigned int r = u + 0x7fffu + ((u >> 16) & 1u);
    return (unsigned short)(r >> 16);
}
__device__ __forceinline__ float bf2f(unsigned short x) {
    return __uint_as_float((unsigned)x << 16);
}

// MFMA-fragment pack offset for element (row, d) of a [R][256] bf16 matrix.
__device__ __forceinline__ size_t pack_off(int row, int d) {
    return ((size_t)(row >> 4) * 8 + (d >> 5)) * 512 +
           (((d >> 3) & 3) * 16 + (row & 15)) * 8 + (d & 7);
}

// ---------------- K0: setup (U/V vectors | B splits) ----------------
__global__ __launch_bounds__(256) void setup_kernel(
    const float* __restrict__ W, const float* __restrict__ W_r,
    const float* __restrict__ a, const float* __restrict__ nw,
    float* __restrict__ U8, double* __restrict__ u0,
    float* __restrict__ V8, double* __restrict__ v0,
    unsigned short* __restrict__ b1h,
    unsigned short* __restrict__ b2h, unsigned short* __restrict__ b2l,
    unsigned short* __restrict__ b3h)
{
    const int bid = blockIdx.x;
    const int tid = threadIdx.x;
    if (bid == 0) {
        int d = tid;
        #pragma unroll
        for (int h = 0; h < N_HEADS; ++h) {
            float ss = 0.f, sd = 0.f;
            #pragma unroll
            for (int e = 0; e < HEAD_DIM; ++e) {
                float w = W[h * 16384 + d * 64 + e];
                ss += w * a[h * 192 + e];
                sd += w * a[h * 192 + 64 + e];
            }
            U8[d * 8 + h] = ss;
            U8[d * 8 + 4 + h] = sd;
        }
        double s0 = 0.0;
        #pragma unroll
        for (int e = 0; e < HEAD_DIM; ++e)
            s0 += (double)W[d * 64 + e] * (double)a[e];
        u0[d] = s0;
    } else if (bid == 1) {
        int d = tid;
        #pragma unroll
        for (int h = 0; h < N_HEADS; ++h) {
            float sv = 0.f;
            #pragma unroll
            for (int e = 0; e < HEAD_DIM; ++e)
                sv += W_r[h * 16384 + d * 64 + e] * a[h * 192 + 128 + e];
            V8[d * 8 + h] = sv;
            V8[d * 8 + 4 + h] = 0.f;
        }
        double s0 = 0.0;
        #pragma unroll
        for (int e = 0; e < HEAD_DIM; ++e)
            s0 += (double)W_r[d * 64 + e] * (double)a[128 + e];
        v0[d] = s0;
    } else {
        // B splits for col n into packed fragment layout
        int n = bid - 2;     // output col
        int k = tid;         // inner dim
        int h = n >> 6, e = n & 63;
        float x1 = W[h * 16384 + k * 64 + e];
        float x2 = nw[k * 256 + n];
        float x3 = W_r[h * 16384 + k * 64 + e];
        size_t off = pack_off(n, k);
        b1h[off] = bf16_rne(x1);
        unsigned short h2 = bf16_rne(x2);
        b2h[off] = h2; b2l[off] = bf16_rne(x2 - bf2f(h2));
        b3h[off] = bf16_rne(x3);
    }
}

// ---------------- K1: rank-1 scores + packed bf16 split (ent blocks 0..511, rel blocks 512..514) ----------------
__global__ __launch_bounds__(256) void ss_kernel(
    const float* __restrict__ ent, const float* __restrict__ relm,
    const float* __restrict__ U8, const double* __restrict__ u0,
    const float* __restrict__ V8, const double* __restrict__ v0,
    float* __restrict__ SS, double* __restrict__ ssrc0, unsigned short* __restrict__ apk,
    float* __restrict__ SSR, double* __restrict__ sr0, unsigned short* __restrict__ rpk)
{
    const int tid = threadIdx.x;
    const int l = tid & 63;
    const int el = l & 31;
    const int q2 = l >> 5;

    const bool isent = blockIdx.x < 512;
    const float* X = isent ? ent : relm;
    const float* U8v = isent ? U8 : V8;
    const double* u0v = isent ? u0 : v0;
    float* SSout = isent ? SS : SSR;
    double* s0out = isent ? ssrc0 : sr0;
    unsigned short* Xpk = isent ? apk : rpk;
    const int N = isent ? N_ENT : N_REL;
    const int wave = isent ? ((blockIdx.x * 256 + tid) >> 6)
                           : (((blockIdx.x - 512) * 256 + tid) >> 6);
    const int nwaves = isent ? 2048 : 12;

    float uu[8][8];
    #pragma unroll
    for (int i = 0; i < 8; ++i) {
        float4 a4 = *(const float4*)(U8v + (el * 8 + i) * 8);
        float4 b4 = *(const float4*)(U8v + (el * 8 + i) * 8 + 4);
        uu[i][0] = a4.x; uu[i][1] = a4.y; uu[i][2] = a4.z; uu[i][3] = a4.w;
        uu[i][4] = b4.x; uu[i][5] = b4.y; uu[i][6] = b4.z; uu[i][7] = b4.w;
    }
    double ud[8];
    #pragma unroll
    for (int i = 0; i < 8; ++i) ud[i] = u0v[el * 8 + i];

    for (int p = wave; p < N / 2; p += nwaves) {
        int n = p * 2 + q2;
        float4 x1 = *(const float4*)(X + (size_t)n * 256 + el * 8);
        float4 x2 = *(const float4*)(X + (size_t)n * 256 + el * 8 + 4);
        float xs[8] = {x1.x, x1.y, x1.z, x1.w, x2.x, x2.y, x2.z, x2.w};

        short8v ov;
        #pragma unroll
        for (int i = 0; i < 8; ++i) ov[i] = (short)bf16_rne(xs[i]);
        *(short8v*)(Xpk + pack_off(n, el * 8)) = ov;

        float pj[8] = {0.f, 0.f, 0.f, 0.f, 0.f, 0.f, 0.f, 0.f};
        double pd = 0.0;
        #pragma unroll
        for (int i = 0; i < 8; ++i) {
            #pragma unroll
            for (int j = 0; j < 8; ++j) pj[j] += xs[i] * uu[i][j];
            pd += (double)xs[i] * ud[i];
        }
        #pragma unroll
        for (int off = 1; off < 32; off <<= 1) {
            #pragma unroll
            for (int j = 0; j < 8; ++j) pj[j] += __shfl_xor(pj[j], off);
            pd += __shfl_xor(pd, off);
        }
        if (el == 0) {
            float4 o1; o1.x = pj[0]; o1.y = pj[1]; o1.z = pj[2]; o1.w = pj[3];
            float4 o2; o2.x = pj[4]; o2.y = pj[5]; o2.z = pj[6]; o2.w = pj[7];
            *(float4*)(SSout + (size_t)n * 8) = o1;
            *(float4*)(SSout + (size_t)n * 8 + 4) = o2;
            s0out[n] = pd;
        }
    }
}

// ---------------- K2: packed-fragment MFMA GEMM, B hi only, bf16 out ----------------
// blocks [0, nb1): A1 -> C1 (M1 rows); blocks [nb1, nb1+nb2): A2 -> C2 (M2 rows)
__global__ __launch_bounds__(256, 4) void gemm_hi(
    const unsigned short* __restrict__ A1, const unsigned short* __restrict__ B1,
    unsigned short* __restrict__ C1, int M1, int nb1,
    const unsigned short* __restrict__ A2, const unsigned short* __restrict__ B2,
    unsigned short* __restrict__ C2, int M2)
{
    const int tid = threadIdx.x;
    const int l = tid & 63;
    const int w = tid >> 6;
    const int rl = l & 15;
    const int ql = l >> 4;

    const int b = blockIdx.x;
    const unsigned short* Apk = (b < nb1) ? A1 : A2;
    const unsigned short* Bh  = (b < nb1) ? B1 : B2;
    unsigned short* C         = (b < nb1) ? C1 : C2;
    const int M               = (b < nb1) ? M1 : M2;
    const int bm              = ((b < nb1) ? b : (b - nb1)) * 64;

    const unsigned short* ab = Apk + (size_t)(bm >> 4) * 4096 + l * 8;
    const unsigned short* bhb = Bh + (size_t)w * 16384 + l * 8;

    f32x4 acc[4][4];
    #pragma unroll
    for (int i = 0; i < 4; ++i)
        #pragma unroll
        for (int j = 0; j < 4; ++j) acc[i][j] = (f32x4){0.f, 0.f, 0.f, 0.f};

    #pragma unroll
    for (int ks = 0; ks < 8; ++ks) {
        short8v ah[4], bh[4];
        #pragma unroll
        for (int mf = 0; mf < 4; ++mf)
            ah[mf] = *(const short8v*)(ab + mf * 4096 + ks * 512);
        #pragma unroll
        for (int nf = 0; nf < 4; ++nf)
            bh[nf] = *(const short8v*)(bhb + nf * 4096 + ks * 512);
        #pragma unroll
        for (int mf = 0; mf < 4; ++mf)
            #pragma unroll
            for (int nf = 0; nf < 4; ++nf)
                acc[mf][nf] = __builtin_amdgcn_mfma_f32_16x16x32_bf16(ah[mf], bh[nf], acc[mf][nf], 0, 0, 0);
    }

    #pragma unroll
    for (int mf = 0; mf < 4; ++mf) {
        int row0 = bm + mf * 16 + ql * 4;
        #pragma unroll
        for (int nf = 0; nf < 4; ++nf) {
            int c = w * 64 + nf * 16 + rl;
            #pragma unroll
            for (int j = 0; j < 4; ++j) {
                int r = row0 + j;
                if (r < M)
                    C[(size_t)r * 256 + c] = bf16_rne(acc[mf][nf][j]);
            }
        }
    }
}

// ---------------- K5: packed-fragment MFMA GEMM, B hi+lo, f32 tanh out ----------------
__global__ __launch_bounds__(256, 4) void gemm_out(
    const unsigned short* __restrict__ Apk,
    const unsigned short* __restrict__ Bpkh, const unsigned short* __restrict__ Bpkl,
    float* __restrict__ Cout, int M)
{
    const int tid = threadIdx.x;
    const int l = tid & 63;
    const int w = tid >> 6;
    const int bm = blockIdx.x * 64;
    const int rl = l & 15;
    const int ql = l >> 4;

    const unsigned short* ab = Apk + (size_t)(bm >> 4) * 4096 + l * 8;
    const unsigned short* bhb = Bpkh + (size_t)w * 16384 + l * 8;
    const unsigned short* blb = Bpkl + (size_t)w * 16384 + l * 8;

    f32x4 acc[4][4];
    #pragma unroll
    for (int i = 0; i < 4; ++i)
        #pragma unroll
        for (int j = 0; j < 4; ++j) acc[i][j] = (f32x4){0.f, 0.f, 0.f, 0.f};

    #pragma unroll 4
    for (int ks = 0; ks < 8; ++ks) {
        short8v ah[4], bh[4], bl[4];
        #pragma unroll
        for (int mf = 0; mf < 4; ++mf)
            ah[mf] = *(const short8v*)(ab + mf * 4096 + ks * 512);
        #pragma unroll
        for (int nf = 0; nf < 4; ++nf) {
            bh[nf] = *(const short8v*)(bhb + nf * 4096 + ks * 512);
            bl[nf] = *(const short8v*)(blb + nf * 4096 + ks * 512);
        }
        #pragma unroll
        for (int mf = 0; mf < 4; ++mf)
            #pragma unroll
            for (int nf = 0; nf < 4; ++nf) {
                acc[mf][nf] = __builtin_amdgcn_mfma_f32_16x16x32_bf16(ah[mf], bh[nf], acc[mf][nf], 0, 0, 0);
                acc[mf][nf] = __builtin_amdgcn_mfma_f32_16x16x32_bf16(ah[mf], bl[nf], acc[mf][nf], 0, 0, 0);
            }
    }

    #pragma unroll
    for (int mf = 0; mf < 4; ++mf) {
        int row0 = bm + mf * 16 + ql * 4;
        #pragma unroll
        for (int nf = 0; nf < 4; ++nf) {
            int c = w * 64 + nf * 16 + rl;
            #pragma unroll
            for (int j = 0; j < 4; ++j) {
                int r = row0 + j;
                if (r < M) {
                    float v = acc[mf][nf][j];
                    Cout[(size_t)r * 256 + c] = 1.f - 2.f / (__expf(2.f * v) + 1.f);
                }
            }
        }
    }
}

// ---------------- K3: top-k select + softmax weights ----------------
__global__ __launch_bounds__(256) void select_kernel(
    const int* __restrict__ src, const int* __restrict__ relid,
    const float* __restrict__ SS, const double* __restrict__ ssrc0,
    const float* __restrict__ SSR, const double* __restrict__ sr0,
    unsigned* __restrict__ idxp, float* __restrict__ wq)
{
    __shared__ __align__(16) float sr4s[N_REL * 4];
    __shared__ double sr0s[N_REL];
    for (int i = threadIdx.x; i < N_REL; i += 256) {
        *(float4*)&sr4s[i * 4] = *(const float4*)&SSR[i * 8];
        sr0s[i] = sr0[i];
    }
    __syncthreads();

    const int tid = threadIdx.x;
    const int l = tid & 63;
    const int el = l & 31;
    const int hb = l & 32;
    const int n = blockIdx.x * 8 + (tid >> 5);

    const int sd_ = src[n * DEG + el];
    const int rd_ = relid[n * DEG + el];
    const double sc0 = ssrc0[sd_] + sr0s[rd_];

    int cnt = 0;
    #pragma unroll
    for (int j = 0; j < DEG; ++j) {
        double sj = __shfl(sc0, hb | j);
        cnt += (sj > sc0 || (sj == sc0 && j < el)) ? 1 : 0;
    }
    const bool sel = (cnt < TOPK);
    const unsigned mask = (unsigned)(__ballot(sel) >> hb);

    float scx = -1e30f, scy = -1e30f, scz = -1e30f, scw = -1e30f;
    if (sel) {
        float4 ssv = *(const float4*)(SS + (size_t)sd_ * 8);
        float4 srv = *(const float4*)&sr4s[rd_ * 4];
        float4 sdv = *(const float4*)(SS + (size_t)n * 8 + 4);
        scx = leaky(ssv.x + sdv.x + srv.x);
        scy = leaky(ssv.y + sdv.y + srv.y);
        scz = leaky(ssv.z + sdv.z + srv.z);
        scw = leaky(ssv.w + sdv.w + srv.w);
    }

    float mx = scx, my = scy, mz = scz, mw = scw;
    #pragma unroll
    for (int off = 1; off < 32; off <<= 1) {
        mx = fmaxf(mx, __shfl_xor(mx, off));
        my = fmaxf(my, __shfl_xor(my, off));
        mz = fmaxf(mz, __shfl_xor(mz, off));
        mw = fmaxf(mw, __shfl_xor(mw, off));
    }
    float ex = sel ? __expf(scx - mx) : 0.f;
    float ey = sel ? __expf(scy - my) : 0.f;
    float ez = sel ? __expf(scz - mz) : 0.f;
    float ew = sel ? __expf(scw - mw) : 0.f;
    float sx = ex, sy = ey, sz = ez, sw = ew;
    #pragma unroll
    for (int off = 1; off < 32; off <<= 1) {
        sx += __shfl_xor(sx, off);
        sy += __shfl_xor(sy, off);
        sz += __shfl_xor(sz, off);
        sw += __shfl_xor(sw, off);
    }

    if (sel) {
        int pos = __popc(mask & ((1u << el) - 1u));
        idxp[n * TOPK + pos] = (unsigned)sd_ | ((unsigned)rd_ << 16);
        float* wqn = wq + (size_t)n * 40;
        wqn[0 * TOPK + pos] = ex / sx;
        wqn[1 * TOPK + pos] = ey / sy;
        wqn[2 * TOPK + pos] = ez / sz;
        wqn[3 * TOPK + pos] = ew / sw;
    }
}

// ---------------- K4: gather-aggregate with hoisted loads ----------------
// 32 lanes per node (8 dims/lane), 8 nodes per block; packed output
__global__ __launch_bounds__(256, 4) void aggr_kernel(
    const unsigned* __restrict__ idxp, const float* __restrict__ wq,
    const unsigned short* __restrict__ emb_bf, const unsigned short* __restrict__ rel_bf,
    unsigned short* __restrict__ napk)
{
    const int tid = threadIdx.x;
    const int el = tid & 31;
    const int n = blockIdx.x * 8 + (tid >> 5);
    const int h = el >> 3;

    unsigned id[TOPK];
    float wgt[TOPK];
    const unsigned* ip = idxp + (size_t)n * TOPK;
    const float* wp = wq + (size_t)n * 40 + h * TOPK;
    #pragma unroll
    for (int k = 0; k < TOPK; ++k) { id[k] = ip[k]; wgt[k] = wp[k]; }

    float acc[8] = {0.f, 0.f, 0.f, 0.f, 0.f, 0.f, 0.f, 0.f};
    #pragma unroll
    for (int c = 0; c < 2; ++c) {
        short8v ev[5], rv[5];
        #pragma unroll
        for (int k = 0; k < 5; ++k) {
            unsigned idk = id[c * 5 + k];
            ev[k] = *(const short8v*)(emb_bf + (size_t)(idk & 0xFFFF) * 256 + el * 8);
            rv[k] = *(const short8v*)(rel_bf + (size_t)(idk >> 16) * 256 + el * 8);
        }
        #pragma unroll
        for (int k = 0; k < 5; ++k) {
            float w = wgt[c * 5 + k];
            #pragma unroll
            for (int j = 0; j < 8; ++j)
                acc[j] += w * (bf2f((unsigned short)ev[k][j]) + bf2f((unsigned short)rv[k][j]));
        }
    }

    short8v ov;
    #pragma unroll
    for (int j = 0; j < 8; ++j) ov[j] = (short)bf16_rne(acc[j]);
    *(short8v*)(napk + pack_off(n, el * 8)) = ov;
}

extern "C" void kernel_launch(void* const* d_in, const int* in_sizes, int n_in,
                              void* d_out, int out_size, void* d_ws, size_t ws_size,
                              hipStream_t stream) {
    const float* ent  = (const float*)d_in[0];
    const float* rel  = (const float*)d_in[1];
    const float* W    = (const float*)d_in[2];
    const float* W_r  = (const float*)d_in[3];
    const float* a    = (const float*)d_in[4];
    const float* nw   = (const float*)d_in[5];
    const int*   srcp = (const int*)d_in[6];
    const int*   ridp = (const int*)d_in[7];
    float* out = (float*)d_out;

    if (ws_size < WS_NEED) return;

    char* ws = (char*)d_ws;
    double* ssrc0 = (double*)(ws + OFF_SSRC0);
    double* sr0   = (double*)(ws + OFF_SR0);
    double* u0    = (double*)(ws + OFF_U0);
    double* v0    = (double*)(ws + OFF_V0);
    float*  SS    = (float*)(ws + OFF_SS);
    float*  SSR   = (float*)(ws + OFF_SSR);
    float*  U8    = (float*)(ws + OFF_U8);
    float*  V8    = (float*)(ws + OFF_V8);
    unsigned short* b1h = (unsigned short*)(ws + OFF_B1H);
    unsigned short* b2h = (unsigned short*)(ws + OFF_B2H);
    unsigned short* b2l = (unsigned short*)(ws + OFF_B2L);
    unsigned short* b3h = (unsigned short*)(ws + OFF_B3H);
    unsigned short* rpk = (unsigned short*)(ws + OFF_RPK);
    unsigned short* apk = (unsigned short*)(ws + OFF_EAH);
    unsigned short* embbf = (unsigned short*)(ws + OFF_EMBBF);
    unsigned short* relbf = (unsigned short*)(ws + OFF_RELBF);
    unsigned* idxp = (unsigned*)(ws + OFF_IDX);
    float*    wqp  = (float*)(ws + OFF_WQ);
    // neigh-packed aliases ent-packed (dead after gemm_hi)
    unsigned short* napk = apk;

    setup_kernel<<<258, 256, 0, stream>>>(W, W_r, a, nw, U8, u0, V8, v0,
                                          b1h, b2h, b2l, b3h);
    ss_kernel<<<515, 256, 0, stream>>>(ent, rel, U8, u0, V8, v0,
                                       SS, ssrc0, apk, SSR, sr0, rpk);
    gemm_hi<<<790, 256, 0, stream>>>(apk, b1h, embbf, N_ENT, 782,
                                     rpk, b3h, relbf, N_REL);
    select_kernel<<<6250, 256, 0, stream>>>(srcp, ridp, SS, ssrc0, SSR, sr0, idxp, wqp);
    aggr_kernel<<<6250, 256, 0, stream>>>(idxp, wqp, embbf, relbf, napk);
    gemm_out<<<782, 256, 0, stream>>>(napk, b2h, b2l, out, N_ENT);
}

// Round 9
// 181.796 us; speedup vs baseline: 1.0871x; 1.0417x over previous
//
#include <hip/hip_runtime.h>
#include <math.h>

#define N_ENT 50000
#define N_REL 500
#define DEG 32
#define TOPK 10
#define H_DIM 256
#define N_HEADS 4
#define HEAD_DIM 64

typedef __attribute__((ext_vector_type(8))) short short8v;
typedef __attribute__((ext_vector_type(4))) float f32x4;

// ---------------- workspace layout (bytes) ----------------
constexpr size_t OFF_SSRC0 = 0;                      // f64 [N_ENT]
constexpr size_t OFF_SR0   = 400000;                 // f64 [N_REL]
constexpr size_t OFF_U0    = 404000;                 // f64 [256]
constexpr size_t OFF_V0    = 406048;                 // f64 [256]
constexpr size_t OFF_SS    = 408096;                 // f32 [N_ENT][8]
constexpr size_t OFF_SSR   = 2008096;                // f32 [N_REL][8] (cols 0..3 = sr4)
constexpr size_t OFF_U8    = 2024096;                // f32 [256][8]
constexpr size_t OFF_V8    = 2032288;                // f32 [256][8]
constexpr size_t OFF_B1H   = 2040480;                // bf16 packed 131072 B each
constexpr size_t OFF_B1L   = 2171552;                // (unused)
constexpr size_t OFF_B2H   = 2302624;
constexpr size_t OFF_B2L   = 2433696;
constexpr size_t OFF_B3H   = 2564768;
constexpr size_t OFF_B3L   = 2695840;                // (unused)
constexpr size_t OFF_RPK   = 2826912;                // bf16 packed rel rows (512) 262144 B
constexpr size_t OFF_EAH   = 3089056;                // bf16 packed A (ent; later neigh) 25,624,576 B
constexpr size_t OFF_EMBBF = 28713632;               // bf16 [N_ENT][256] emb_t (row-major)
constexpr size_t OFF_RELBF = 54313632;               // bf16 [N_REL][256]
constexpr size_t OFF_IDX   = 54569632;               // u32 [N_ENT][10]
constexpr size_t OFF_WQ    = 56569632;               // f32 [N_ENT][4][10]
constexpr size_t WS_NEED   = 64569632;               // ~62 MB

__device__ __forceinline__ float leaky(float x) { return x >= 0.f ? x : 0.2f * x; }

__device__ __forceinline__ unsigned short bf16_rne(float x) {
    unsigned int u = __float_as_uint(x);
    unsigned int r = u + 0x7fffu + ((u >> 16) & 1u);
    return (unsigned short)(r >> 16);
}
__device__ __forceinline__ float bf2f(unsigned short x) {
    return __uint_as_float((unsigned)x << 16);
}

// MFMA-fragment pack offset for element (row, d) of a [R][256] bf16 matrix.
__device__ __forceinline__ size_t pack_off(int row, int d) {
    return ((size_t)(row >> 4) * 8 + (d >> 5)) * 512 +
           (((d >> 3) & 3) * 16 + (row & 15)) * 8 + (d & 7);
}

// ---------------- K0: setup (U/V vectors | B splits) ----------------
__global__ __launch_bounds__(256) void setup_kernel(
    const float* __restrict__ W, const float* __restrict__ W_r,
    const float* __restrict__ a, const float* __restrict__ nw,
    float* __restrict__ U8, double* __restrict__ u0,
    float* __restrict__ V8, double* __restrict__ v0,
    unsigned short* __restrict__ b1h,
    unsigned short* __restrict__ b2h, unsigned short* __restrict__ b2l,
    unsigned short* __restrict__ b3h)
{
    const int bid = blockIdx.x;
    const int tid = threadIdx.x;
    if (bid == 0) {
        int d = tid;
        #pragma unroll
        for (int h = 0; h < N_HEADS; ++h) {
            float ss = 0.f, sd = 0.f;
            #pragma unroll
            for (int e = 0; e < HEAD_DIM; ++e) {
                float w = W[h * 16384 + d * 64 + e];
                ss += w * a[h * 192 + e];
                sd += w * a[h * 192 + 64 + e];
            }
            U8[d * 8 + h] = ss;
            U8[d * 8 + 4 + h] = sd;
        }
        double s0 = 0.0;
        #pragma unroll
        for (int e = 0; e < HEAD_DIM; ++e)
            s0 += (double)W[d * 64 + e] * (double)a[e];
        u0[d] = s0;
    } else if (bid == 1) {
        int d = tid;
        #pragma unroll
        for (int h = 0; h < N_HEADS; ++h) {
            float sv = 0.f;
            #pragma unroll
            for (int e = 0; e < HEAD_DIM; ++e)
                sv += W_r[h * 16384 + d * 64 + e] * a[h * 192 + 128 + e];
            V8[d * 8 + h] = sv;
            V8[d * 8 + 4 + h] = 0.f;
        }
        double s0 = 0.0;
        #pragma unroll
        for (int e = 0; e < HEAD_DIM; ++e)
            s0 += (double)W_r[d * 64 + e] * (double)a[128 + e];
        v0[d] = s0;
    } else {
        // B splits for col n into packed fragment layout
        int n = bid - 2;     // output col
        int k = tid;         // inner dim
        int h = n >> 6, e = n & 63;
        float x1 = W[h * 16384 + k * 64 + e];
        float x2 = nw[k * 256 + n];
        float x3 = W_r[h * 16384 + k * 64 + e];
        size_t off = pack_off(n, k);
        b1h[off] = bf16_rne(x1);
        unsigned short h2 = bf16_rne(x2);
        b2h[off] = h2; b2l[off] = bf16_rne(x2 - bf2f(h2));
        b3h[off] = bf16_rne(x3);
    }
}

// ---------------- K1: rank-1 scores + packed bf16 split ----------------
// ent blocks [0,2048), rel blocks [2048,2111). Fold-reduction: 9 f32 shuffles.
__global__ __launch_bounds__(256) void ss_kernel(
    const float* __restrict__ ent, const float* __restrict__ relm,
    const float* __restrict__ U8, const double* __restrict__ u0,
    const float* __restrict__ V8, const double* __restrict__ v0,
    float* __restrict__ SS, double* __restrict__ ssrc0, unsigned short* __restrict__ apk,
    float* __restrict__ SSR, double* __restrict__ sr0, unsigned short* __restrict__ rpk)
{
    const int tid = threadIdx.x;
    const int l = tid & 63;
    const int el = l & 31;
    const int q2 = l >> 5;

    const bool isent = blockIdx.x < 2048;
    const float* X = isent ? ent : relm;
    const float* U8v = isent ? U8 : V8;
    const double* u0v = isent ? u0 : v0;
    float* SSout = isent ? SS : SSR;
    double* s0out = isent ? ssrc0 : sr0;
    unsigned short* Xpk = isent ? apk : rpk;
    const int N = isent ? N_ENT : N_REL;
    const int wave = isent ? ((blockIdx.x * 256 + tid) >> 6)
                           : (((blockIdx.x - 2048) * 256 + tid) >> 6);
    const int nwaves = isent ? 8192 : 252;

    // this lane's U slice (row-invariant)
    float uu[8][8];
    #pragma unroll
    for (int i = 0; i < 8; ++i) {
        float4 a4 = *(const float4*)(U8v + (el * 8 + i) * 8);
        float4 b4 = *(const float4*)(U8v + (el * 8 + i) * 8 + 4);
        uu[i][0] = a4.x; uu[i][1] = a4.y; uu[i][2] = a4.z; uu[i][3] = a4.w;
        uu[i][4] = b4.x; uu[i][5] = b4.y; uu[i][6] = b4.z; uu[i][7] = b4.w;
    }
    double ud[8];
    #pragma unroll
    for (int i = 0; i < 8; ++i) ud[i] = u0v[el * 8 + i];

    // output column owned by lane el (<8) after the fold
    const int jout = ((el & 1) << 2) | (el & 2) | ((el >> 2) & 1);

    for (int p = wave; p < N / 2; p += nwaves) {
        int n = p * 2 + q2;
        float4 x1 = *(const float4*)(X + (size_t)n * 256 + el * 8);
        float4 x2 = *(const float4*)(X + (size_t)n * 256 + el * 8 + 4);
        float xs[8] = {x1.x, x1.y, x1.z, x1.w, x2.x, x2.y, x2.z, x2.w};

        short8v ov;
        #pragma unroll
        for (int i = 0; i < 8; ++i) ov[i] = (short)bf16_rne(xs[i]);
        *(short8v*)(Xpk + pack_off(n, el * 8)) = ov;

        float pj[8] = {0.f, 0.f, 0.f, 0.f, 0.f, 0.f, 0.f, 0.f};
        double pd = 0.0;
        #pragma unroll
        for (int i = 0; i < 8; ++i) {
            #pragma unroll
            for (int j = 0; j < 8; ++j) pj[j] += xs[i] * uu[i][j];
            pd += (double)xs[i] * ud[i];
        }

        // fold-reduce 8 f32 over 32 lanes: 8->4->2->1, then 2 plain steps
        const bool b1 = (el & 1);
        float q[4];
        #pragma unroll
        for (int j = 0; j < 4; ++j) {
            float mine = b1 ? pj[j + 4] : pj[j];
            float send = b1 ? pj[j] : pj[j + 4];
            q[j] = mine + __shfl_xor(send, 1);
        }
        const bool b2 = (el & 2);
        float r2[2];
        #pragma unroll
        for (int j = 0; j < 2; ++j) {
            float mine = b2 ? q[j + 2] : q[j];
            float send = b2 ? q[j] : q[j + 2];
            r2[j] = mine + __shfl_xor(send, 2);
        }
        const bool b4 = (el & 4);
        {
            float mine = b4 ? r2[1] : r2[0];
            float send = b4 ? r2[0] : r2[1];
            r2[0] = mine + __shfl_xor(send, 4);
        }
        r2[0] += __shfl_xor(r2[0], 8);
        r2[0] += __shfl_xor(r2[0], 16);

        // f64 plain butterfly (1 value)
        #pragma unroll
        for (int off = 1; off < 32; off <<= 1) pd += __shfl_xor(pd, off);

        if (el < 8) SSout[(size_t)n * 8 + jout] = r2[0];
        if (el == 0) s0out[n] = pd;
    }
}

// ---------------- K2: packed-fragment MFMA GEMM, B hi only, bf16 out ----------------
__global__ __launch_bounds__(256, 4) void gemm_hi(
    const unsigned short* __restrict__ A1, const unsigned short* __restrict__ B1,
    unsigned short* __restrict__ C1, int M1, int nb1,
    const unsigned short* __restrict__ A2, const unsigned short* __restrict__ B2,
    unsigned short* __restrict__ C2, int M2)
{
    const int tid = threadIdx.x;
    const int l = tid & 63;
    const int w = tid >> 6;
    const int rl = l & 15;
    const int ql = l >> 4;

    const int b = blockIdx.x;
    const unsigned short* Apk = (b < nb1) ? A1 : A2;
    const unsigned short* Bh  = (b < nb1) ? B1 : B2;
    unsigned short* C         = (b < nb1) ? C1 : C2;
    const int M               = (b < nb1) ? M1 : M2;
    const int bm              = ((b < nb1) ? b : (b - nb1)) * 64;

    const unsigned short* ab = Apk + (size_t)(bm >> 4) * 4096 + l * 8;
    const unsigned short* bhb = Bh + (size_t)w * 16384 + l * 8;

    f32x4 acc[4][4];
    #pragma unroll
    for (int i = 0; i < 4; ++i)
        #pragma unroll
        for (int j = 0; j < 4; ++j) acc[i][j] = (f32x4){0.f, 0.f, 0.f, 0.f};

    #pragma unroll
    for (int ks = 0; ks < 8; ++ks) {
        short8v ah[4], bh[4];
        #pragma unroll
        for (int mf = 0; mf < 4; ++mf)
            ah[mf] = *(const short8v*)(ab + mf * 4096 + ks * 512);
        #pragma unroll
        for (int nf = 0; nf < 4; ++nf)
            bh[nf] = *(const short8v*)(bhb + nf * 4096 + ks * 512);
        #pragma unroll
        for (int mf = 0; mf < 4; ++mf)
            #pragma unroll
            for (int nf = 0; nf < 4; ++nf)
                acc[mf][nf] = __builtin_amdgcn_mfma_f32_16x16x32_bf16(ah[mf], bh[nf], acc[mf][nf], 0, 0, 0);
    }

    #pragma unroll
    for (int mf = 0; mf < 4; ++mf) {
        int row0 = bm + mf * 16 + ql * 4;
        #pragma unroll
        for (int nf = 0; nf < 4; ++nf) {
            int c = w * 64 + nf * 16 + rl;
            #pragma unroll
            for (int j = 0; j < 4; ++j) {
                int r = row0 + j;
                if (r < M)
                    C[(size_t)r * 256 + c] = bf16_rne(acc[mf][nf][j]);
            }
        }
    }
}

// ---------------- K5: packed-fragment MFMA GEMM, B hi+lo, f32 tanh out ----------------
__global__ __launch_bounds__(256, 4) void gemm_out(
    const unsigned short* __restrict__ Apk,
    const unsigned short* __restrict__ Bpkh, const unsigned short* __restrict__ Bpkl,
    float* __restrict__ Cout, int M)
{
    const int tid = threadIdx.x;
    const int l = tid & 63;
    const int w = tid >> 6;
    const int bm = blockIdx.x * 64;
    const int rl = l & 15;
    const int ql = l >> 4;

    const unsigned short* ab = Apk + (size_t)(bm >> 4) * 4096 + l * 8;
    const unsigned short* bhb = Bpkh + (size_t)w * 16384 + l * 8;
    const unsigned short* blb = Bpkl + (size_t)w * 16384 + l * 8;

    f32x4 acc[4][4];
    #pragma unroll
    for (int i = 0; i < 4; ++i)
        #pragma unroll
        for (int j = 0; j < 4; ++j) acc[i][j] = (f32x4){0.f, 0.f, 0.f, 0.f};

    #pragma unroll 4
    for (int ks = 0; ks < 8; ++ks) {
        short8v ah[4], bh[4], bl[4];
        #pragma unroll
        for (int mf = 0; mf < 4; ++mf)
            ah[mf] = *(const short8v*)(ab + mf * 4096 + ks * 512);
        #pragma unroll
        for (int nf = 0; nf < 4; ++nf) {
            bh[nf] = *(const short8v*)(bhb + nf * 4096 + ks * 512);
            bl[nf] = *(const short8v*)(blb + nf * 4096 + ks * 512);
        }
        #pragma unroll
        for (int mf = 0; mf < 4; ++mf)
            #pragma unroll
            for (int nf = 0; nf < 4; ++nf) {
                acc[mf][nf] = __builtin_amdgcn_mfma_f32_16x16x32_bf16(ah[mf], bh[nf], acc[mf][nf], 0, 0, 0);
                acc[mf][nf] = __builtin_amdgcn_mfma_f32_16x16x32_bf16(ah[mf], bl[nf], acc[mf][nf], 0, 0, 0);
            }
    }

    #pragma unroll
    for (int mf = 0; mf < 4; ++mf) {
        int row0 = bm + mf * 16 + ql * 4;
        #pragma unroll
        for (int nf = 0; nf < 4; ++nf) {
            int c = w * 64 + nf * 16 + rl;
            #pragma unroll
            for (int j = 0; j < 4; ++j) {
                int r = row0 + j;
                if (r < M) {
                    float v = acc[mf][nf][j];
                    Cout[(size_t)r * 256 + c] = 1.f - 2.f / (__expf(2.f * v) + 1.f);
                }
            }
        }
    }
}

// ---------------- K3: top-k select + softmax weights ----------------
__global__ __launch_bounds__(256) void select_kernel(
    const int* __restrict__ src, const int* __restrict__ relid,
    const float* __restrict__ SS, const double* __restrict__ ssrc0,
    const float* __restrict__ SSR, const double* __restrict__ sr0,
    unsigned* __restrict__ idxp, float* __restrict__ wq)
{
    __shared__ __align__(16) float sr4s[N_REL * 4];
    __shared__ double sr0s[N_REL];
    for (int i = threadIdx.x; i < N_REL; i += 256) {
        *(float4*)&sr4s[i * 4] = *(const float4*)&SSR[i * 8];
        sr0s[i] = sr0[i];
    }
    __syncthreads();

    const int tid = threadIdx.x;
    const int l = tid & 63;
    const int el = l & 31;
    const int hb = l & 32;
    const int n = blockIdx.x * 8 + (tid >> 5);

    const int sd_ = src[n * DEG + el];
    const int rd_ = relid[n * DEG + el];
    const double sc0 = ssrc0[sd_] + sr0s[rd_];

    int cnt = 0;
    #pragma unroll
    for (int j = 0; j < DEG; ++j) {
        double sj = __shfl(sc0, hb | j);
        cnt += (sj > sc0 || (sj == sc0 && j < el)) ? 1 : 0;
    }
    const bool sel = (cnt < TOPK);
    const unsigned mask = (unsigned)(__ballot(sel) >> hb);

    float scx = -1e30f, scy = -1e30f, scz = -1e30f, scw = -1e30f;
    if (sel) {
        float4 ssv = *(const float4*)(SS + (size_t)sd_ * 8);
        float4 srv = *(const float4*)&sr4s[rd_ * 4];
        float4 sdv = *(const float4*)(SS + (size_t)n * 8 + 4);
        scx = leaky(ssv.x + sdv.x + srv.x);
        scy = leaky(ssv.y + sdv.y + srv.y);
        scz = leaky(ssv.z + sdv.z + srv.z);
        scw = leaky(ssv.w + sdv.w + srv.w);
    }

    float mx = scx, my = scy, mz = scz, mw = scw;
    #pragma unroll
    for (int off = 1; off < 32; off <<= 1) {
        mx = fmaxf(mx, __shfl_xor(mx, off));
        my = fmaxf(my, __shfl_xor(my, off));
        mz = fmaxf(mz, __shfl_xor(mz, off));
        mw = fmaxf(mw, __shfl_xor(mw, off));
    }
    float ex = sel ? __expf(scx - mx) : 0.f;
    float ey = sel ? __expf(scy - my) : 0.f;
    float ez = sel ? __expf(scz - mz) : 0.f;
    float ew = sel ? __expf(scw - mw) : 0.f;
    float sx = ex, sy = ey, sz = ez, sw = ew;
    #pragma unroll
    for (int off = 1; off < 32; off <<= 1) {
        sx += __shfl_xor(sx, off);
        sy += __shfl_xor(sy, off);
        sz += __shfl_xor(sz, off);
        sw += __shfl_xor(sw, off);
    }

    if (sel) {
        int pos = __popc(mask & ((1u << el) - 1u));
        idxp[n * TOPK + pos] = (unsigned)sd_ | ((unsigned)rd_ << 16);
        float* wqn = wq + (size_t)n * 40;
        wqn[0 * TOPK + pos] = ex / sx;
        wqn[1 * TOPK + pos] = ey / sy;
        wqn[2 * TOPK + pos] = ez / sz;
        wqn[3 * TOPK + pos] = ew / sw;
    }
}

// ---------------- K4: gather-aggregate with hoisted loads ----------------
__global__ __launch_bounds__(256, 4) void aggr_kernel(
    const unsigned* __restrict__ idxp, const float* __restrict__ wq,
    const unsigned short* __restrict__ emb_bf, const unsigned short* __restrict__ rel_bf,
    unsigned short* __restrict__ napk)
{
    const int tid = threadIdx.x;
    const int el = tid & 31;
    const int n = blockIdx.x * 8 + (tid >> 5);
    const int h = el >> 3;

    unsigned id[TOPK];
    float wgt[TOPK];
    const unsigned* ip = idxp + (size_t)n * TOPK;
    const float* wp = wq + (size_t)n * 40 + h * TOPK;
    #pragma unroll
    for (int k = 0; k < TOPK; ++k) { id[k] = ip[k]; wgt[k] = wp[k]; }

    float acc[8] = {0.f, 0.f, 0.f, 0.f, 0.f, 0.f, 0.f, 0.f};
    #pragma unroll
    for (int c = 0; c < 2; ++c) {
        short8v ev[5], rv[5];
        #pragma unroll
        for (int k = 0; k < 5; ++k) {
            unsigned idk = id[c * 5 + k];
            ev[k] = *(const short8v*)(emb_bf + (size_t)(idk & 0xFFFF) * 256 + el * 8);
            rv[k] = *(const short8v*)(rel_bf + (size_t)(idk >> 16) * 256 + el * 8);
        }
        #pragma unroll
        for (int k = 0; k < 5; ++k) {
            float w = wgt[c * 5 + k];
            #pragma unroll
            for (int j = 0; j < 8; ++j)
                acc[j] += w * (bf2f((unsigned short)ev[k][j]) + bf2f((unsigned short)rv[k][j]));
        }
    }

    short8v ov;
    #pragma unroll
    for (int j = 0; j < 8; ++j) ov[j] = (short)bf16_rne(acc[j]);
    *(short8v*)(napk + pack_off(n, el * 8)) = ov;
}

extern "C" void kernel_launch(void* const* d_in, const int* in_sizes, int n_in,
                              void* d_out, int out_size, void* d_ws, size_t ws_size,
                              hipStream_t stream) {
    const float* ent  = (const float*)d_in[0];
    const float* rel  = (const float*)d_in[1];
    const float* W    = (const float*)d_in[2];
    const float* W_r  = (const float*)d_in[3];
    const float* a    = (const float*)d_in[4];
    const float* nw   = (const float*)d_in[5];
    const int*   srcp = (const int*)d_in[6];
    const int*   ridp = (const int*)d_in[7];
    float* out = (float*)d_out;

    if (ws_size < WS_NEED) return;

    char* ws = (char*)d_ws;
    double* ssrc0 = (double*)(ws + OFF_SSRC0);
    double* sr0   = (double*)(ws + OFF_SR0);
    double* u0    = (double*)(ws + OFF_U0);
    double* v0    = (double*)(ws + OFF_V0);
    float*  SS    = (float*)(ws + OFF_SS);
    float*  SSR   = (float*)(ws + OFF_SSR);
    float*  U8    = (float*)(ws + OFF_U8);
    float*  V8    = (float*)(ws + OFF_V8);
    unsigned short* b1h = (unsigned short*)(ws + OFF_B1H);
    unsigned short* b2h = (unsigned short*)(ws + OFF_B2H);
    unsigned short* b2l = (unsigned short*)(ws + OFF_B2L);
    unsigned short* b3h = (unsigned short*)(ws + OFF_B3H);
    unsigned short* rpk = (unsigned short*)(ws + OFF_RPK);
    unsigned short* apk = (unsigned short*)(ws + OFF_EAH);
    unsigned short* embbf = (unsigned short*)(ws + OFF_EMBBF);
    unsigned short* relbf = (unsigned short*)(ws + OFF_RELBF);
    unsigned* idxp = (unsigned*)(ws + OFF_IDX);
    float*    wqp  = (float*)(ws + OFF_WQ);
    // neigh-packed aliases ent-packed (dead after gemm_hi)
    unsigned short* napk = apk;

    setup_kernel<<<258, 256, 0, stream>>>(W, W_r, a, nw, U8, u0, V8, v0,
                                          b1h, b2h, b2l, b3h);
    ss_kernel<<<2111, 256, 0, stream>>>(ent, rel, U8, u0, V8, v0,
                                        SS, ssrc0, apk, SSR, sr0, rpk);
    gemm_hi<<<790, 256, 0, stream>>>(apk, b1h, embbf, N_ENT, 782,
                                     rpk, b3h, relbf, N_REL);
    select_kernel<<<6250, 256, 0, stream>>>(srcp, ridp, SS, ssrc0, SSR, sr0, idxp, wqp);
    aggr_kernel<<<6250, 256, 0, stream>>>(idxp, wqp, embbf, relbf, napk);
    gemm_out<<<782, 256, 0, stream>>>(napk, b2h, b2l, out, N_ENT);
}

// Round 10
// 167.656 us; speedup vs baseline: 1.1788x; 1.0843x over previous
//
#include <hip/hip_runtime.h>
#include <math.h>

#define N_ENT 50000
#define N_REL 500
#define DEG 32
#define TOPK 10
#define H_DIM 256
#define N_HEADS 4
#define HEAD_DIM 64

typedef __attribute__((ext_vector_type(8))) short short8v;
typedef __attribute__((ext_vector_type(4))) float f32x4;

// ---------------- workspace layout (bytes) ----------------
constexpr size_t OFF_SSRC0 = 0;                      // f64 [N_ENT]
constexpr size_t OFF_SR0   = 400000;                 // f64 [N_REL]
constexpr size_t OFF_U0    = 404000;                 // f64 [256]
constexpr size_t OFF_V0    = 406048;                 // f64 [256]
constexpr size_t OFF_SS    = 408096;                 // f32 [N_ENT][8]
constexpr size_t OFF_SSR   = 2008096;                // f32 [N_REL][8] (cols 0..3 = sr4)
constexpr size_t OFF_U8    = 2024096;                // f32 [256][8]
constexpr size_t OFF_V8    = 2032288;                // f32 [256][8]
constexpr size_t OFF_B1H   = 2040480;                // bf16 packed 131072 B each
constexpr size_t OFF_B2H   = 2302624;
constexpr size_t OFF_B3H   = 2564768;
constexpr size_t OFF_RPK   = 2826912;                // bf16 packed rel rows (512) 262144 B
constexpr size_t OFF_EAH   = 3089056;                // bf16 packed A (ent; later neigh) 25,624,576 B
constexpr size_t OFF_EMBBF = 28713632;               // bf16 [N_ENT][256] emb_t (row-major)
constexpr size_t OFF_RELBF = 54313632;               // bf16 [N_REL][256]
constexpr size_t OFF_IDX   = 54569632;               // u32 [N_ENT][10]
constexpr size_t OFF_WQ    = 56569632;               // f32 [N_ENT][4][10]
constexpr size_t WS_NEED   = 64569632;               // ~62 MB

__device__ __forceinline__ float leaky(float x) { return x >= 0.f ? x : 0.2f * x; }

__device__ __forceinline__ unsigned short bf16_rne(float x) {
    unsigned int u = __float_as_uint(x);
    unsigned int r = u + 0x7fffu + ((u >> 16) & 1u);
    return (unsigned short)(r >> 16);
}
__device__ __forceinline__ float bf2f(unsigned short x) {
    return __uint_as_float((unsigned)x << 16);
}

// MFMA-fragment pack offset for element (row, d) of a [R][256] bf16 matrix.
__device__ __forceinline__ size_t pack_off(int row, int d) {
    return ((size_t)(row >> 4) * 8 + (d >> 5)) * 512 +
           (((d >> 3) & 3) * 16 + (row & 15)) * 8 + (d & 7);
}

// ---------------- K0: setup (U/V vectors | B splits) ----------------
__global__ __launch_bounds__(256) void setup_kernel(
    const float* __restrict__ W, const float* __restrict__ W_r,
    const float* __restrict__ a, const float* __restrict__ nw,
    float* __restrict__ U8, double* __restrict__ u0,
    float* __restrict__ V8, double* __restrict__ v0,
    unsigned short* __restrict__ b1h, unsigned short* __restrict__ b2h,
    unsigned short* __restrict__ b3h)
{
    const int bid = blockIdx.x;
    const int tid = threadIdx.x;
    if (bid == 0) {
        int d = tid;
        #pragma unroll
        for (int h = 0; h < N_HEADS; ++h) {
            float ss = 0.f, sd = 0.f;
            #pragma unroll
            for (int e = 0; e < HEAD_DIM; ++e) {
                float w = W[h * 16384 + d * 64 + e];
                ss += w * a[h * 192 + e];
                sd += w * a[h * 192 + 64 + e];
            }
            U8[d * 8 + h] = ss;
            U8[d * 8 + 4 + h] = sd;
        }
        double s0 = 0.0;
        #pragma unroll
        for (int e = 0; e < HEAD_DIM; ++e)
            s0 += (double)W[d * 64 + e] * (double)a[e];
        u0[d] = s0;
    } else if (bid == 1) {
        int d = tid;
        #pragma unroll
        for (int h = 0; h < N_HEADS; ++h) {
            float sv = 0.f;
            #pragma unroll
            for (int e = 0; e < HEAD_DIM; ++e)
                sv += W_r[h * 16384 + d * 64 + e] * a[h * 192 + 128 + e];
            V8[d * 8 + h] = sv;
            V8[d * 8 + 4 + h] = 0.f;
        }
        double s0 = 0.0;
        #pragma unroll
        for (int e = 0; e < HEAD_DIM; ++e)
            s0 += (double)W_r[d * 64 + e] * (double)a[128 + e];
        v0[d] = s0;
    } else {
        int n = bid - 2;     // output col
        int k = tid;         // inner dim
        int h = n >> 6, e = n & 63;
        float x1 = W[h * 16384 + k * 64 + e];
        float x2 = nw[k * 256 + n];
        float x3 = W_r[h * 16384 + k * 64 + e];
        size_t off = pack_off(n, k);
        b1h[off] = bf16_rne(x1);
        b2h[off] = bf16_rne(x2);
        b3h[off] = bf16_rne(x3);
    }
}

// ---------------- K1: rank-1 scores + packed bf16 split ----------------
// ent blocks [0,2048), rel blocks [2048,2111). Fold-reduction: 9 f32 shuffles.
__global__ __launch_bounds__(256) void ss_kernel(
    const float* __restrict__ ent, const float* __restrict__ relm,
    const float* __restrict__ U8, const double* __restrict__ u0,
    const float* __restrict__ V8, const double* __restrict__ v0,
    float* __restrict__ SS, double* __restrict__ ssrc0, unsigned short* __restrict__ apk,
    float* __restrict__ SSR, double* __restrict__ sr0, unsigned short* __restrict__ rpk)
{
    const int tid = threadIdx.x;
    const int l = tid & 63;
    const int el = l & 31;
    const int q2 = l >> 5;

    const bool isent = blockIdx.x < 2048;
    const float* X = isent ? ent : relm;
    const float* U8v = isent ? U8 : V8;
    const double* u0v = isent ? u0 : v0;
    float* SSout = isent ? SS : SSR;
    double* s0out = isent ? ssrc0 : sr0;
    unsigned short* Xpk = isent ? apk : rpk;
    const int N = isent ? N_ENT : N_REL;
    const int wave = isent ? ((blockIdx.x * 256 + tid) >> 6)
                           : (((blockIdx.x - 2048) * 256 + tid) >> 6);
    const int nwaves = isent ? 8192 : 252;

    float uu[8][8];
    #pragma unroll
    for (int i = 0; i < 8; ++i) {
        float4 a4 = *(const float4*)(U8v + (el * 8 + i) * 8);
        float4 b4 = *(const float4*)(U8v + (el * 8 + i) * 8 + 4);
        uu[i][0] = a4.x; uu[i][1] = a4.y; uu[i][2] = a4.z; uu[i][3] = a4.w;
        uu[i][4] = b4.x; uu[i][5] = b4.y; uu[i][6] = b4.z; uu[i][7] = b4.w;
    }
    double ud[8];
    #pragma unroll
    for (int i = 0; i < 8; ++i) ud[i] = u0v[el * 8 + i];

    const int jout = ((el & 1) << 2) | (el & 2) | ((el >> 2) & 1);

    for (int p = wave; p < N / 2; p += nwaves) {
        int n = p * 2 + q2;
        float4 x1 = *(const float4*)(X + (size_t)n * 256 + el * 8);
        float4 x2 = *(const float4*)(X + (size_t)n * 256 + el * 8 + 4);
        float xs[8] = {x1.x, x1.y, x1.z, x1.w, x2.x, x2.y, x2.z, x2.w};

        short8v ov;
        #pragma unroll
        for (int i = 0; i < 8; ++i) ov[i] = (short)bf16_rne(xs[i]);
        *(short8v*)(Xpk + pack_off(n, el * 8)) = ov;

        float pj[8] = {0.f, 0.f, 0.f, 0.f, 0.f, 0.f, 0.f, 0.f};
        double pd = 0.0;
        #pragma unroll
        for (int i = 0; i < 8; ++i) {
            #pragma unroll
            for (int j = 0; j < 8; ++j) pj[j] += xs[i] * uu[i][j];
            pd += (double)xs[i] * ud[i];
        }

        const bool b1 = (el & 1);
        float q[4];
        #pragma unroll
        for (int j = 0; j < 4; ++j) {
            float mine = b1 ? pj[j + 4] : pj[j];
            float send = b1 ? pj[j] : pj[j + 4];
            q[j] = mine + __shfl_xor(send, 1);
        }
        const bool b2 = (el & 2);
        float r2[2];
        #pragma unroll
        for (int j = 0; j < 2; ++j) {
            float mine = b2 ? q[j + 2] : q[j];
            float send = b2 ? q[j] : q[j + 2];
            r2[j] = mine + __shfl_xor(send, 2);
        }
        const bool b4 = (el & 4);
        {
            float mine = b4 ? r2[1] : r2[0];
            float send = b4 ? r2[0] : r2[1];
            r2[0] = mine + __shfl_xor(send, 4);
        }
        r2[0] += __shfl_xor(r2[0], 8);
        r2[0] += __shfl_xor(r2[0], 16);

        #pragma unroll
        for (int off = 1; off < 32; off <<= 1) pd += __shfl_xor(pd, off);

        if (el < 8) SSout[(size_t)n * 8 + jout] = r2[0];
        if (el == 0) s0out[n] = pd;
    }
}

// ---------------- K2: fused {packed MFMA GEMM (hi) | top-k select} ----------------
// blocks [0,nb1): ent GEMM; [nb1,nbg): rel GEMM; [nbg, nbg+6250): select
__global__ __launch_bounds__(256) void mid_kernel(
    const unsigned short* __restrict__ A1, const unsigned short* __restrict__ B1,
    unsigned short* __restrict__ C1, int M1, int nb1,
    const unsigned short* __restrict__ A2, const unsigned short* __restrict__ B2,
    unsigned short* __restrict__ C2, int M2, int nbg,
    const int* __restrict__ src, const int* __restrict__ relid,
    const float* __restrict__ SS, const double* __restrict__ ssrc0,
    const float* __restrict__ SSR, const double* __restrict__ sr0,
    unsigned* __restrict__ idxp, float* __restrict__ wq)
{
    __shared__ __align__(16) float sr4s[N_REL * 4];
    __shared__ double sr0s[N_REL];

    const int tid = threadIdx.x;
    const int b = blockIdx.x;

    if (b < nbg) {
        // ---- GEMM path (B hi only, bf16 out) ----
        const int l = tid & 63;
        const int w = tid >> 6;
        const int rl = l & 15;
        const int ql = l >> 4;

        const unsigned short* Apk = (b < nb1) ? A1 : A2;
        const unsigned short* Bh  = (b < nb1) ? B1 : B2;
        unsigned short* C         = (b < nb1) ? C1 : C2;
        const int M               = (b < nb1) ? M1 : M2;
        const int bm              = ((b < nb1) ? b : (b - nb1)) * 64;

        const unsigned short* ab = Apk + (size_t)(bm >> 4) * 4096 + l * 8;
        const unsigned short* bhb = Bh + (size_t)w * 16384 + l * 8;

        f32x4 acc[4][4];
        #pragma unroll
        for (int i = 0; i < 4; ++i)
            #pragma unroll
            for (int j = 0; j < 4; ++j) acc[i][j] = (f32x4){0.f, 0.f, 0.f, 0.f};

        #pragma unroll
        for (int ks = 0; ks < 8; ++ks) {
            short8v ah[4], bh[4];
            #pragma unroll
            for (int mf = 0; mf < 4; ++mf)
                ah[mf] = *(const short8v*)(ab + mf * 4096 + ks * 512);
            #pragma unroll
            for (int nf = 0; nf < 4; ++nf)
                bh[nf] = *(const short8v*)(bhb + nf * 4096 + ks * 512);
            #pragma unroll
            for (int mf = 0; mf < 4; ++mf)
                #pragma unroll
                for (int nf = 0; nf < 4; ++nf)
                    acc[mf][nf] = __builtin_amdgcn_mfma_f32_16x16x32_bf16(ah[mf], bh[nf], acc[mf][nf], 0, 0, 0);
        }

        #pragma unroll
        for (int mf = 0; mf < 4; ++mf) {
            int row0 = bm + mf * 16 + ql * 4;
            #pragma unroll
            for (int nf = 0; nf < 4; ++nf) {
                int c = w * 64 + nf * 16 + rl;
                #pragma unroll
                for (int j = 0; j < 4; ++j) {
                    int r = row0 + j;
                    if (r < M)
                        C[(size_t)r * 256 + c] = bf16_rne(acc[mf][nf][j]);
                }
            }
        }
    } else {
        // ---- select path ----
        for (int i = tid; i < N_REL; i += 256) {
            *(float4*)&sr4s[i * 4] = *(const float4*)&SSR[i * 8];
            sr0s[i] = sr0[i];
        }
        __syncthreads();

        const int l = tid & 63;
        const int el = l & 31;
        const int hb = l & 32;
        const int n = (b - nbg) * 8 + (tid >> 5);

        const int sd_ = src[n * DEG + el];
        const int rd_ = relid[n * DEG + el];
        const double sc0 = ssrc0[sd_] + sr0s[rd_];

        int cnt = 0;
        #pragma unroll
        for (int j = 0; j < DEG; ++j) {
            double sj = __shfl(sc0, hb | j);
            cnt += (sj > sc0 || (sj == sc0 && j < el)) ? 1 : 0;
        }
        const bool sel = (cnt < TOPK);
        const unsigned mask = (unsigned)(__ballot(sel) >> hb);

        float scx = -1e30f, scy = -1e30f, scz = -1e30f, scw = -1e30f;
        if (sel) {
            float4 ssv = *(const float4*)(SS + (size_t)sd_ * 8);
            float4 srv = *(const float4*)&sr4s[rd_ * 4];
            float4 sdv = *(const float4*)(SS + (size_t)n * 8 + 4);
            scx = leaky(ssv.x + sdv.x + srv.x);
            scy = leaky(ssv.y + sdv.y + srv.y);
            scz = leaky(ssv.z + sdv.z + srv.z);
            scw = leaky(ssv.w + sdv.w + srv.w);
        }

        float mx = scx, my = scy, mz = scz, mw = scw;
        #pragma unroll
        for (int off = 1; off < 32; off <<= 1) {
            mx = fmaxf(mx, __shfl_xor(mx, off));
            my = fmaxf(my, __shfl_xor(my, off));
            mz = fmaxf(mz, __shfl_xor(mz, off));
            mw = fmaxf(mw, __shfl_xor(mw, off));
        }
        float ex = sel ? __expf(scx - mx) : 0.f;
        float ey = sel ? __expf(scy - my) : 0.f;
        float ez = sel ? __expf(scz - mz) : 0.f;
        float ew = sel ? __expf(scw - mw) : 0.f;
        float sx = ex, sy = ey, sz = ez, sw = ew;
        #pragma unroll
        for (int off = 1; off < 32; off <<= 1) {
            sx += __shfl_xor(sx, off);
            sy += __shfl_xor(sy, off);
            sz += __shfl_xor(sz, off);
            sw += __shfl_xor(sw, off);
        }

        if (sel) {
            int pos = __popc(mask & ((1u << el) - 1u));
            idxp[n * TOPK + pos] = (unsigned)sd_ | ((unsigned)rd_ << 16);
            float* wqn = wq + (size_t)n * 40;
            wqn[0 * TOPK + pos] = ex / sx;
            wqn[1 * TOPK + pos] = ey / sy;
            wqn[2 * TOPK + pos] = ez / sz;
            wqn[3 * TOPK + pos] = ew / sw;
        }
    }
}

// ---------------- K3: gather-aggregate, 10-deep emb hoist ----------------
__global__ __launch_bounds__(256, 4) void aggr_kernel(
    const unsigned* __restrict__ idxp, const float* __restrict__ wq,
    const unsigned short* __restrict__ emb_bf, const unsigned short* __restrict__ rel_bf,
    unsigned short* __restrict__ napk)
{
    const int tid = threadIdx.x;
    const int el = tid & 31;
    const int n = blockIdx.x * 8 + (tid >> 5);
    const int h = el >> 3;

    unsigned id[TOPK];
    float wgt[TOPK];
    const unsigned* ip = idxp + (size_t)n * TOPK;
    const float* wp = wq + (size_t)n * 40 + h * TOPK;
    #pragma unroll
    for (int k = 0; k < TOPK; ++k) { id[k] = ip[k]; wgt[k] = wp[k]; }

    // hoist ALL 10 emb gathers (long-latency, L3-bound) into flight at once
    short8v ev[TOPK];
    #pragma unroll
    for (int k = 0; k < TOPK; ++k)
        ev[k] = *(const short8v*)(emb_bf + (size_t)(id[k] & 0xFFFF) * 256 + el * 8);

    // rel rows are L2-hot (256 KB table): stream them through the FMA loop
    float acc[8] = {0.f, 0.f, 0.f, 0.f, 0.f, 0.f, 0.f, 0.f};
    #pragma unroll
    for (int k = 0; k < TOPK; ++k) {
        short8v rv = *(const short8v*)(rel_bf + (size_t)(id[k] >> 16) * 256 + el * 8);
        float w = wgt[k];
        #pragma unroll
        for (int j = 0; j < 8; ++j)
            acc[j] += w * (bf2f((unsigned short)ev[k][j]) + bf2f((unsigned short)rv[j]));
    }

    short8v ov;
    #pragma unroll
    for (int j = 0; j < 8; ++j) ov[j] = (short)bf16_rne(acc[j]);
    *(short8v*)(napk + pack_off(n, el * 8)) = ov;
}

// ---------------- K4: packed MFMA GEMM, B hi only, f32 tanh out ----------------
__global__ __launch_bounds__(256, 4) void gemm_out(
    const unsigned short* __restrict__ Apk, const unsigned short* __restrict__ Bpkh,
    float* __restrict__ Cout, int M)
{
    const int tid = threadIdx.x;
    const int l = tid & 63;
    const int w = tid >> 6;
    const int bm = blockIdx.x * 64;
    const int rl = l & 15;
    const int ql = l >> 4;

    const unsigned short* ab = Apk + (size_t)(bm >> 4) * 4096 + l * 8;
    const unsigned short* bhb = Bpkh + (size_t)w * 16384 + l * 8;

    f32x4 acc[4][4];
    #pragma unroll
    for (int i = 0; i < 4; ++i)
        #pragma unroll
        for (int j = 0; j < 4; ++j) acc[i][j] = (f32x4){0.f, 0.f, 0.f, 0.f};

    #pragma unroll
    for (int ks = 0; ks < 8; ++ks) {
        short8v ah[4], bh[4];
        #pragma unroll
        for (int mf = 0; mf < 4; ++mf)
            ah[mf] = *(const short8v*)(ab + mf * 4096 + ks * 512);
        #pragma unroll
        for (int nf = 0; nf < 4; ++nf)
            bh[nf] = *(const short8v*)(bhb + nf * 4096 + ks * 512);
        #pragma unroll
        for (int mf = 0; mf < 4; ++mf)
            #pragma unroll
            for (int nf = 0; nf < 4; ++nf)
                acc[mf][nf] = __builtin_amdgcn_mfma_f32_16x16x32_bf16(ah[mf], bh[nf], acc[mf][nf], 0, 0, 0);
    }

    #pragma unroll
    for (int mf = 0; mf < 4; ++mf) {
        int row0 = bm + mf * 16 + ql * 4;
        #pragma unroll
        for (int nf = 0; nf < 4; ++nf) {
            int c = w * 64 + nf * 16 + rl;
            #pragma unroll
            for (int j = 0; j < 4; ++j) {
                int r = row0 + j;
                if (r < M) {
                    float v = acc[mf][nf][j];
                    Cout[(size_t)r * 256 + c] = 1.f - 2.f / (__expf(2.f * v) + 1.f);
                }
            }
        }
    }
}

extern "C" void kernel_launch(void* const* d_in, const int* in_sizes, int n_in,
                              void* d_out, int out_size, void* d_ws, size_t ws_size,
                              hipStream_t stream) {
    const float* ent  = (const float*)d_in[0];
    const float* rel  = (const float*)d_in[1];
    const float* W    = (const float*)d_in[2];
    const float* W_r  = (const float*)d_in[3];
    const float* a    = (const float*)d_in[4];
    const float* nw   = (const float*)d_in[5];
    const int*   srcp = (const int*)d_in[6];
    const int*   ridp = (const int*)d_in[7];
    float* out = (float*)d_out;

    if (ws_size < WS_NEED) return;

    char* ws = (char*)d_ws;
    double* ssrc0 = (double*)(ws + OFF_SSRC0);
    double* sr0   = (double*)(ws + OFF_SR0);
    double* u0    = (double*)(ws + OFF_U0);
    double* v0    = (double*)(ws + OFF_V0);
    float*  SS    = (float*)(ws + OFF_SS);
    float*  SSR   = (float*)(ws + OFF_SSR);
    float*  U8    = (float*)(ws + OFF_U8);
    float*  V8    = (float*)(ws + OFF_V8);
    unsigned short* b1h = (unsigned short*)(ws + OFF_B1H);
    unsigned short* b2h = (unsigned short*)(ws + OFF_B2H);
    unsigned short* b3h = (unsigned short*)(ws + OFF_B3H);
    unsigned short* rpk = (unsigned short*)(ws + OFF_RPK);
    unsigned short* apk = (unsigned short*)(ws + OFF_EAH);
    unsigned short* embbf = (unsigned short*)(ws + OFF_EMBBF);
    unsigned short* relbf = (unsigned short*)(ws + OFF_RELBF);
    unsigned* idxp = (unsigned*)(ws + OFF_IDX);
    float*    wqp  = (float*)(ws + OFF_WQ);
    unsigned short* napk = apk;   // neigh-packed aliases ent-packed

    setup_kernel<<<258, 256, 0, stream>>>(W, W_r, a, nw, U8, u0, V8, v0,
                                          b1h, b2h, b3h);
    ss_kernel<<<2111, 256, 0, stream>>>(ent, rel, U8, u0, V8, v0,
                                        SS, ssrc0, apk, SSR, sr0, rpk);
    mid_kernel<<<7040, 256, 0, stream>>>(apk, b1h, embbf, N_ENT, 782,
                                         rpk, b3h, relbf, N_REL, 790,
                                         srcp, ridp, SS, ssrc0, SSR, sr0, idxp, wqp);
    aggr_kernel<<<6250, 256, 0, stream>>>(idxp, wqp, embbf, relbf, napk);
    gemm_out<<<782, 256, 0, stream>>>(napk, b2h, out, N_ENT);
}

// Round 11
// 155.430 us; speedup vs baseline: 1.2716x; 1.0787x over previous
//
#include <hip/hip_runtime.h>
#include <math.h>

#define N_ENT 50000
#define N_REL 500
#define DEG 32
#define TOPK 10
#define H_DIM 256
#define N_HEADS 4
#define HEAD_DIM 64

typedef __attribute__((ext_vector_type(8))) short short8v;
typedef __attribute__((ext_vector_type(4))) float f32x4;

// ---------------- workspace layout (bytes) ----------------
constexpr size_t OFF_SSRC0 = 0;                      // f64 [N_ENT]
constexpr size_t OFF_SR0   = 400000;                 // f64 [N_REL]
constexpr size_t OFF_U0    = 404000;                 // f64 [256]
constexpr size_t OFF_V0    = 406048;                 // f64 [256]
constexpr size_t OFF_SS    = 408096;                 // f32 [N_ENT][8]
constexpr size_t OFF_SSR   = 2008096;                // f32 [N_REL][8] (cols 0..3 = sr4)
constexpr size_t OFF_U8    = 2024096;                // f32 [256][8]
constexpr size_t OFF_V8    = 2032288;                // f32 [256][8]
constexpr size_t OFF_B1H   = 2040480;                // bf16 packed 131072 B each
constexpr size_t OFF_B2H   = 2302624;
constexpr size_t OFF_B3H   = 2564768;
constexpr size_t OFF_RPK   = 2826912;                // bf16 packed rel rows (512) 262144 B
constexpr size_t OFF_EAH   = 3089056;                // bf16 packed A (ent; later neigh) 25,624,576 B
constexpr size_t OFF_EMBBF = 28713632;               // bf16 [N_ENT][256] emb_t (row-major)
constexpr size_t OFF_RELBF = 54313632;               // bf16 [N_REL][256]
constexpr size_t WS_NEED   = 54569632;               // ~52 MB

__device__ __forceinline__ float leaky(float x) { return x >= 0.f ? x : 0.2f * x; }

__device__ __forceinline__ unsigned short bf16_rne(float x) {
    unsigned int u = __float_as_uint(x);
    unsigned int r = u + 0x7fffu + ((u >> 16) & 1u);
    return (unsigned short)(r >> 16);
}
__device__ __forceinline__ float bf2f(unsigned short x) {
    return __uint_as_float((unsigned)x << 16);
}

// MFMA-fragment pack offset for element (row, d) of a [R][256] bf16 matrix.
__device__ __forceinline__ size_t pack_off(int row, int d) {
    return ((size_t)(row >> 4) * 8 + (d >> 5)) * 512 +
           (((d >> 3) & 3) * 16 + (row & 15)) * 8 + (d & 7);
}

// ---------------- K0: setup (U/V vectors | B splits) ----------------
__global__ __launch_bounds__(256) void setup_kernel(
    const float* __restrict__ W, const float* __restrict__ W_r,
    const float* __restrict__ a, const float* __restrict__ nw,
    float* __restrict__ U8, double* __restrict__ u0,
    float* __restrict__ V8, double* __restrict__ v0,
    unsigned short* __restrict__ b1h, unsigned short* __restrict__ b2h,
    unsigned short* __restrict__ b3h)
{
    const int bid = blockIdx.x;
    const int tid = threadIdx.x;
    if (bid == 0) {
        int d = tid;
        #pragma unroll
        for (int h = 0; h < N_HEADS; ++h) {
            float ss = 0.f, sd = 0.f;
            #pragma unroll
            for (int e = 0; e < HEAD_DIM; ++e) {
                float w = W[h * 16384 + d * 64 + e];
                ss += w * a[h * 192 + e];
                sd += w * a[h * 192 + 64 + e];
            }
            U8[d * 8 + h] = ss;
            U8[d * 8 + 4 + h] = sd;
        }
        double s0 = 0.0;
        #pragma unroll
        for (int e = 0; e < HEAD_DIM; ++e)
            s0 += (double)W[d * 64 + e] * (double)a[e];
        u0[d] = s0;
    } else if (bid == 1) {
        int d = tid;
        #pragma unroll
        for (int h = 0; h < N_HEADS; ++h) {
            float sv = 0.f;
            #pragma unroll
            for (int e = 0; e < HEAD_DIM; ++e)
                sv += W_r[h * 16384 + d * 64 + e] * a[h * 192 + 128 + e];
            V8[d * 8 + h] = sv;
            V8[d * 8 + 4 + h] = 0.f;
        }
        double s0 = 0.0;
        #pragma unroll
        for (int e = 0; e < HEAD_DIM; ++e)
            s0 += (double)W_r[d * 64 + e] * (double)a[128 + e];
        v0[d] = s0;
    } else {
        int n = bid - 2;     // output col
        int k = tid;         // inner dim
        int h = n >> 6, e = n & 63;
        float x1 = W[h * 16384 + k * 64 + e];
        float x2 = nw[k * 256 + n];
        float x3 = W_r[h * 16384 + k * 64 + e];
        size_t off = pack_off(n, k);
        b1h[off] = bf16_rne(x1);
        b2h[off] = bf16_rne(x2);
        b3h[off] = bf16_rne(x3);
    }
}

// ---------------- K1: rank-1 scores + packed bf16 split ----------------
// ent blocks [0,2048), rel blocks [2048,2111). Fold-reduction: 9 f32 shuffles.
__global__ __launch_bounds__(256) void ss_kernel(
    const float* __restrict__ ent, const float* __restrict__ relm,
    const float* __restrict__ U8, const double* __restrict__ u0,
    const float* __restrict__ V8, const double* __restrict__ v0,
    float* __restrict__ SS, double* __restrict__ ssrc0, unsigned short* __restrict__ apk,
    float* __restrict__ SSR, double* __restrict__ sr0, unsigned short* __restrict__ rpk)
{
    const int tid = threadIdx.x;
    const int l = tid & 63;
    const int el = l & 31;
    const int q2 = l >> 5;

    const bool isent = blockIdx.x < 2048;
    const float* X = isent ? ent : relm;
    const float* U8v = isent ? U8 : V8;
    const double* u0v = isent ? u0 : v0;
    float* SSout = isent ? SS : SSR;
    double* s0out = isent ? ssrc0 : sr0;
    unsigned short* Xpk = isent ? apk : rpk;
    const int N = isent ? N_ENT : N_REL;
    const int wave = isent ? ((blockIdx.x * 256 + tid) >> 6)
                           : (((blockIdx.x - 2048) * 256 + tid) >> 6);
    const int nwaves = isent ? 8192 : 252;

    float uu[8][8];
    #pragma unroll
    for (int i = 0; i < 8; ++i) {
        float4 a4 = *(const float4*)(U8v + (el * 8 + i) * 8);
        float4 b4 = *(const float4*)(U8v + (el * 8 + i) * 8 + 4);
        uu[i][0] = a4.x; uu[i][1] = a4.y; uu[i][2] = a4.z; uu[i][3] = a4.w;
        uu[i][4] = b4.x; uu[i][5] = b4.y; uu[i][6] = b4.z; uu[i][7] = b4.w;
    }
    double ud[8];
    #pragma unroll
    for (int i = 0; i < 8; ++i) ud[i] = u0v[el * 8 + i];

    const int jout = ((el & 1) << 2) | (el & 2) | ((el >> 2) & 1);

    for (int p = wave; p < N / 2; p += nwaves) {
        int n = p * 2 + q2;
        float4 x1 = *(const float4*)(X + (size_t)n * 256 + el * 8);
        float4 x2 = *(const float4*)(X + (size_t)n * 256 + el * 8 + 4);
        float xs[8] = {x1.x, x1.y, x1.z, x1.w, x2.x, x2.y, x2.z, x2.w};

        short8v ov;
        #pragma unroll
        for (int i = 0; i < 8; ++i) ov[i] = (short)bf16_rne(xs[i]);
        *(short8v*)(Xpk + pack_off(n, el * 8)) = ov;

        float pj[8] = {0.f, 0.f, 0.f, 0.f, 0.f, 0.f, 0.f, 0.f};
        double pd = 0.0;
        #pragma unroll
        for (int i = 0; i < 8; ++i) {
            #pragma unroll
            for (int j = 0; j < 8; ++j) pj[j] += xs[i] * uu[i][j];
            pd += (double)xs[i] * ud[i];
        }

        const bool b1 = (el & 1);
        float q[4];
        #pragma unroll
        for (int j = 0; j < 4; ++j) {
            float mine = b1 ? pj[j + 4] : pj[j];
            float send = b1 ? pj[j] : pj[j + 4];
            q[j] = mine + __shfl_xor(send, 1);
        }
        const bool b2 = (el & 2);
        float r2[2];
        #pragma unroll
        for (int j = 0; j < 2; ++j) {
            float mine = b2 ? q[j + 2] : q[j];
            float send = b2 ? q[j] : q[j + 2];
            r2[j] = mine + __shfl_xor(send, 2);
        }
        const bool b4 = (el & 4);
        {
            float mine = b4 ? r2[1] : r2[0];
            float send = b4 ? r2[0] : r2[1];
            r2[0] = mine + __shfl_xor(send, 4);
        }
        r2[0] += __shfl_xor(r2[0], 8);
        r2[0] += __shfl_xor(r2[0], 16);

        #pragma unroll
        for (int off = 1; off < 32; off <<= 1) pd += __shfl_xor(pd, off);

        if (el < 8) SSout[(size_t)n * 8 + jout] = r2[0];
        if (el == 0) s0out[n] = pd;
    }
}

// ---------------- K2: packed MFMA GEMM, B hi only, bf16 out (ent + rel) ----------------
__global__ __launch_bounds__(256, 4) void gemm_hi(
    const unsigned short* __restrict__ A1, const unsigned short* __restrict__ B1,
    unsigned short* __restrict__ C1, int M1, int nb1,
    const unsigned short* __restrict__ A2, const unsigned short* __restrict__ B2,
    unsigned short* __restrict__ C2, int M2)
{
    const int tid = threadIdx.x;
    const int l = tid & 63;
    const int w = tid >> 6;
    const int rl = l & 15;
    const int ql = l >> 4;

    const int b = blockIdx.x;
    const unsigned short* Apk = (b < nb1) ? A1 : A2;
    const unsigned short* Bh  = (b < nb1) ? B1 : B2;
    unsigned short* C         = (b < nb1) ? C1 : C2;
    const int M               = (b < nb1) ? M1 : M2;
    const int bm              = ((b < nb1) ? b : (b - nb1)) * 64;

    const unsigned short* ab = Apk + (size_t)(bm >> 4) * 4096 + l * 8;
    const unsigned short* bhb = Bh + (size_t)w * 16384 + l * 8;

    f32x4 acc[4][4];
    #pragma unroll
    for (int i = 0; i < 4; ++i)
        #pragma unroll
        for (int j = 0; j < 4; ++j) acc[i][j] = (f32x4){0.f, 0.f, 0.f, 0.f};

    #pragma unroll
    for (int ks = 0; ks < 8; ++ks) {
        short8v ah[4], bh[4];
        #pragma unroll
        for (int mf = 0; mf < 4; ++mf)
            ah[mf] = *(const short8v*)(ab + mf * 4096 + ks * 512);
        #pragma unroll
        for (int nf = 0; nf < 4; ++nf)
            bh[nf] = *(const short8v*)(bhb + nf * 4096 + ks * 512);
        #pragma unroll
        for (int mf = 0; mf < 4; ++mf)
            #pragma unroll
            for (int nf = 0; nf < 4; ++nf)
                acc[mf][nf] = __builtin_amdgcn_mfma_f32_16x16x32_bf16(ah[mf], bh[nf], acc[mf][nf], 0, 0, 0);
    }

    #pragma unroll
    for (int mf = 0; mf < 4; ++mf) {
        int row0 = bm + mf * 16 + ql * 4;
        #pragma unroll
        for (int nf = 0; nf < 4; ++nf) {
            int c = w * 64 + nf * 16 + rl;
            #pragma unroll
            for (int j = 0; j < 4; ++j) {
                int r = row0 + j;
                if (r < M)
                    C[(size_t)r * 256 + c] = bf16_rne(acc[mf][nf][j]);
            }
        }
    }
}

// ---------------- K3: fused top-k select + softmax + gather-aggregate ----------------
// 32 lanes per node, 8 nodes per block; packed bf16 output
__global__ __launch_bounds__(256, 3) void node_kernel(
    const int* __restrict__ src, const int* __restrict__ relid,
    const float* __restrict__ SS, const double* __restrict__ ssrc0,
    const float* __restrict__ SSR, const double* __restrict__ sr0,
    const unsigned short* __restrict__ emb_bf, const unsigned short* __restrict__ rel_bf,
    unsigned short* __restrict__ napk)
{
    __shared__ __align__(16) float sr4s[N_REL * 4];
    __shared__ double sr0s[N_REL];
    __shared__ float wls[8][32][4];   // unnormalized exp weights per node-in-block

    const int tid = threadIdx.x;
    for (int i = tid; i < N_REL; i += 256) {
        *(float4*)&sr4s[i * 4] = *(const float4*)&SSR[i * 8];
        sr0s[i] = sr0[i];
    }
    __syncthreads();

    const int l = tid & 63;
    const int el = l & 31;
    const int hb = l & 32;
    const int nib = tid >> 5;
    const int n = blockIdx.x * 8 + nib;

    const int sd_ = src[n * DEG + el];
    const int rd_ = relid[n * DEG + el];
    const double sc0 = ssrc0[sd_] + sr0s[rd_];

    // rank by count (stable: lower index wins ties == jax.lax.top_k)
    int cnt = 0;
    #pragma unroll
    for (int j = 0; j < DEG; ++j) {
        double sj = __shfl(sc0, hb | j);
        cnt += (sj > sc0 || (sj == sc0 && j < el)) ? 1 : 0;
    }
    const bool sel = (cnt < TOPK);
    const unsigned mask = (unsigned)(__ballot(sel) >> hb);

    float scx = -1e30f, scy = -1e30f, scz = -1e30f, scw = -1e30f;
    if (sel) {
        float4 ssv = *(const float4*)(SS + (size_t)sd_ * 8);
        float4 srv = *(const float4*)&sr4s[rd_ * 4];
        float4 sdv = *(const float4*)(SS + (size_t)n * 8 + 4);
        scx = leaky(ssv.x + sdv.x + srv.x);
        scy = leaky(ssv.y + sdv.y + srv.y);
        scz = leaky(ssv.z + sdv.z + srv.z);
        scw = leaky(ssv.w + sdv.w + srv.w);
    }

    float mx = scx, my = scy, mz = scz, mw = scw;
    #pragma unroll
    for (int off = 1; off < 32; off <<= 1) {
        mx = fmaxf(mx, __shfl_xor(mx, off));
        my = fmaxf(my, __shfl_xor(my, off));
        mz = fmaxf(mz, __shfl_xor(mz, off));
        mw = fmaxf(mw, __shfl_xor(mw, off));
    }
    float ex = sel ? __expf(scx - mx) : 0.f;
    float ey = sel ? __expf(scy - my) : 0.f;
    float ez = sel ? __expf(scz - mz) : 0.f;
    float ew = sel ? __expf(scw - mw) : 0.f;
    float sx = ex, sy = ey, sz = ez, sw = ew;
    #pragma unroll
    for (int off = 1; off < 32; off <<= 1) {
        sx += __shfl_xor(sx, off);
        sy += __shfl_xor(sy, off);
        sz += __shfl_xor(sz, off);
        sw += __shfl_xor(sw, off);
    }

    if (sel) {
        float4 wv; wv.x = ex; wv.y = ey; wv.z = ez; wv.w = ew;
        *(float4*)&wls[nib][el][0] = wv;
    }
    __syncthreads();

    // ---- aggregation: lane el covers dims el*8..el*8+7 (head h) of node n ----
    const int h = el >> 3;
    const float sh = h == 0 ? sx : h == 1 ? sy : h == 2 ? sz : sw;
    const float rsh = 1.f / sh;

    // extract the 10 selected lane indices + ids
    int lks[TOPK], sk[TOPK], rk[TOPK];
    unsigned mm = mask;
    #pragma unroll
    for (int k = 0; k < TOPK; ++k) {
        lks[k] = __builtin_ctz(mm);
        mm &= mm - 1;
        sk[k] = __shfl(sd_, hb | lks[k]);
        rk[k] = __shfl(rd_, hb | lks[k]);
    }

    // hoist ALL 10 emb gathers (long-latency) into flight
    short8v ev[TOPK];
    #pragma unroll
    for (int k = 0; k < TOPK; ++k)
        ev[k] = *(const short8v*)(emb_bf + (size_t)sk[k] * 256 + el * 8);

    float acc[8] = {0.f, 0.f, 0.f, 0.f, 0.f, 0.f, 0.f, 0.f};
    #pragma unroll
    for (int k = 0; k < TOPK; ++k) {
        short8v rv = *(const short8v*)(rel_bf + (size_t)rk[k] * 256 + el * 8);
        float w = wls[nib][lks[k]][h] * rsh;
        #pragma unroll
        for (int j = 0; j < 8; ++j)
            acc[j] += w * (bf2f((unsigned short)ev[k][j]) + bf2f((unsigned short)rv[j]));
    }

    short8v ov;
    #pragma unroll
    for (int j = 0; j < 8; ++j) ov[j] = (short)bf16_rne(acc[j]);
    *(short8v*)(napk + pack_off(n, el * 8)) = ov;
}

// ---------------- K4: packed MFMA GEMM, B hi only, f32 tanh out ----------------
__global__ __launch_bounds__(256, 4) void gemm_out(
    const unsigned short* __restrict__ Apk, const unsigned short* __restrict__ Bpkh,
    float* __restrict__ Cout, int M)
{
    const int tid = threadIdx.x;
    const int l = tid & 63;
    const int w = tid >> 6;
    const int bm = blockIdx.x * 64;
    const int rl = l & 15;
    const int ql = l >> 4;

    const unsigned short* ab = Apk + (size_t)(bm >> 4) * 4096 + l * 8;
    const unsigned short* bhb = Bpkh + (size_t)w * 16384 + l * 8;

    f32x4 acc[4][4];
    #pragma unroll
    for (int i = 0; i < 4; ++i)
        #pragma unroll
        for (int j = 0; j < 4; ++j) acc[i][j] = (f32x4){0.f, 0.f, 0.f, 0.f};

    #pragma unroll
    for (int ks = 0; ks < 8; ++ks) {
        short8v ah[4], bh[4];
        #pragma unroll
        for (int mf = 0; mf < 4; ++mf)
            ah[mf] = *(const short8v*)(ab + mf * 4096 + ks * 512);
        #pragma unroll
        for (int nf = 0; nf < 4; ++nf)
            bh[nf] = *(const short8v*)(bhb + nf * 4096 + ks * 512);
        #pragma unroll
        for (int mf = 0; mf < 4; ++mf)
            #pragma unroll
            for (int nf = 0; nf < 4; ++nf)
                acc[mf][nf] = __builtin_amdgcn_mfma_f32_16x16x32_bf16(ah[mf], bh[nf], acc[mf][nf], 0, 0, 0);
    }

    #pragma unroll
    for (int mf = 0; mf < 4; ++mf) {
        int row0 = bm + mf * 16 + ql * 4;
        #pragma unroll
        for (int nf = 0; nf < 4; ++nf) {
            int c = w * 64 + nf * 16 + rl;
            #pragma unroll
            for (int j = 0; j < 4; ++j) {
                int r = row0 + j;
                if (r < M) {
                    float v = acc[mf][nf][j];
                    Cout[(size_t)r * 256 + c] = 1.f - 2.f / (__expf(2.f * v) + 1.f);
                }
            }
        }
    }
}

extern "C" void kernel_launch(void* const* d_in, const int* in_sizes, int n_in,
                              void* d_out, int out_size, void* d_ws, size_t ws_size,
                              hipStream_t stream) {
    const float* ent  = (const float*)d_in[0];
    const float* rel  = (const float*)d_in[1];
    const float* W    = (const float*)d_in[2];
    const float* W_r  = (const float*)d_in[3];
    const float* a    = (const float*)d_in[4];
    const float* nw   = (const float*)d_in[5];
    const int*   srcp = (const int*)d_in[6];
    const int*   ridp = (const int*)d_in[7];
    float* out = (float*)d_out;

    if (ws_size < WS_NEED) return;

    char* ws = (char*)d_ws;
    double* ssrc0 = (double*)(ws + OFF_SSRC0);
    double* sr0   = (double*)(ws + OFF_SR0);
    double* u0    = (double*)(ws + OFF_U0);
    double* v0    = (double*)(ws + OFF_V0);
    float*  SS    = (float*)(ws + OFF_SS);
    float*  SSR   = (float*)(ws + OFF_SSR);
    float*  U8    = (float*)(ws + OFF_U8);
    float*  V8    = (float*)(ws + OFF_V8);
    unsigned short* b1h = (unsigned short*)(ws + OFF_B1H);
    unsigned short* b2h = (unsigned short*)(ws + OFF_B2H);
    unsigned short* b3h = (unsigned short*)(ws + OFF_B3H);
    unsigned short* rpk = (unsigned short*)(ws + OFF_RPK);
    unsigned short* apk = (unsigned short*)(ws + OFF_EAH);
    unsigned short* embbf = (unsigned short*)(ws + OFF_EMBBF);
    unsigned short* relbf = (unsigned short*)(ws + OFF_RELBF);
    unsigned short* napk = apk;   // neigh-packed aliases ent-packed (dead after gemm_hi)

    setup_kernel<<<258, 256, 0, stream>>>(W, W_r, a, nw, U8, u0, V8, v0,
                                          b1h, b2h, b3h);
    ss_kernel<<<2111, 256, 0, stream>>>(ent, rel, U8, u0, V8, v0,
                                        SS, ssrc0, apk, SSR, sr0, rpk);
    gemm_hi<<<790, 256, 0, stream>>>(apk, b1h, embbf, N_ENT, 782,
                                     rpk, b3h, relbf, N_REL);
    node_kernel<<<6250, 256, 0, stream>>>(srcp, ridp, SS, ssrc0, SSR, sr0,
                                          embbf, relbf, napk);
    gemm_out<<<782, 256, 0, stream>>>(napk, b2h, out, N_ENT);
}

// Round 12
// 146.893 us; speedup vs baseline: 1.3455x; 1.0581x over previous
//
#include <hip/hip_runtime.h>
#include <math.h>

#define N_ENT 50000
#define N_REL 500
#define DEG 32
#define TOPK 10
#define H_DIM 256
#define N_HEADS 4
#define HEAD_DIM 64

typedef __attribute__((ext_vector_type(8))) short short8v;
typedef __attribute__((ext_vector_type(4))) float f32x4;

// ---------------- workspace layout (bytes) ----------------
constexpr size_t OFF_SSRC0 = 0;                      // f64 [N_ENT]
constexpr size_t OFF_SR0   = 400000;                 // f64 [N_REL]
constexpr size_t OFF_U0    = 404000;                 // f64 [256]
constexpr size_t OFF_V0    = 406048;                 // f64 [256]
constexpr size_t OFF_SS    = 408096;                 // f32 [N_ENT][8]
constexpr size_t OFF_SSR   = 2008096;                // f32 [N_REL][8] (cols 0..3 = sr4)
constexpr size_t OFF_U8    = 2024096;                // f32 [256][8]
constexpr size_t OFF_V8    = 2032288;                // f32 [256][8]
constexpr size_t OFF_B1H   = 2040480;                // bf16 packed 131072 B each
constexpr size_t OFF_B2H   = 2302624;
constexpr size_t OFF_B3H   = 2564768;
constexpr size_t OFF_RPK   = 2826912;                // bf16 packed rel rows (512) 262144 B
constexpr size_t OFF_EAH   = 3089056;                // bf16 packed A (ent; later neigh) 25,624,576 B
constexpr size_t OFF_EMBBF = 28713632;               // bf16 [N_ENT][256] emb_t (row-major)
constexpr size_t OFF_RELBF = 54313632;               // bf16 [N_REL][256]
constexpr size_t WS_NEED   = 54569632;               // ~52 MB

__device__ __forceinline__ float leaky(float x) { return x >= 0.f ? x : 0.2f * x; }

__device__ __forceinline__ unsigned short bf16_rne(float x) {
    unsigned int u = __float_as_uint(x);
    unsigned int r = u + 0x7fffu + ((u >> 16) & 1u);
    return (unsigned short)(r >> 16);
}
__device__ __forceinline__ float bf2f(unsigned short x) {
    return __uint_as_float((unsigned)x << 16);
}

// MFMA-fragment pack offset for element (row, d) of a [R][256] bf16 matrix.
__device__ __forceinline__ size_t pack_off(int row, int d) {
    return ((size_t)(row >> 4) * 8 + (d >> 5)) * 512 +
           (((d >> 3) & 3) * 16 + (row & 15)) * 8 + (d & 7);
}

// ---------------- K0: setup (U/V vectors | B splits) ----------------
__global__ __launch_bounds__(256) void setup_kernel(
    const float* __restrict__ W, const float* __restrict__ W_r,
    const float* __restrict__ a, const float* __restrict__ nw,
    float* __restrict__ U8, double* __restrict__ u0,
    float* __restrict__ V8, double* __restrict__ v0,
    unsigned short* __restrict__ b1h, unsigned short* __restrict__ b2h,
    unsigned short* __restrict__ b3h)
{
    const int bid = blockIdx.x;
    const int tid = threadIdx.x;
    if (bid == 0) {
        int d = tid;
        #pragma unroll
        for (int h = 0; h < N_HEADS; ++h) {
            float ss = 0.f, sd = 0.f;
            #pragma unroll
            for (int e = 0; e < HEAD_DIM; ++e) {
                float w = W[h * 16384 + d * 64 + e];
                ss += w * a[h * 192 + e];
                sd += w * a[h * 192 + 64 + e];
            }
            U8[d * 8 + h] = ss;
            U8[d * 8 + 4 + h] = sd;
        }
        double s0 = 0.0;
        #pragma unroll
        for (int e = 0; e < HEAD_DIM; ++e)
            s0 += (double)W[d * 64 + e] * (double)a[e];
        u0[d] = s0;
    } else if (bid == 1) {
        int d = tid;
        #pragma unroll
        for (int h = 0; h < N_HEADS; ++h) {
            float sv = 0.f;
            #pragma unroll
            for (int e = 0; e < HEAD_DIM; ++e)
                sv += W_r[h * 16384 + d * 64 + e] * a[h * 192 + 128 + e];
            V8[d * 8 + h] = sv;
            V8[d * 8 + 4 + h] = 0.f;
        }
        double s0 = 0.0;
        #pragma unroll
        for (int e = 0; e < HEAD_DIM; ++e)
            s0 += (double)W_r[d * 64 + e] * (double)a[128 + e];
        v0[d] = s0;
    } else {
        int n = bid - 2;     // output col
        int k = tid;         // inner dim
        int h = n >> 6, e = n & 63;
        float x1 = W[h * 16384 + k * 64 + e];
        float x2 = nw[k * 256 + n];
        float x3 = W_r[h * 16384 + k * 64 + e];
        size_t off = pack_off(n, k);
        b1h[off] = bf16_rne(x1);
        b2h[off] = bf16_rne(x2);
        b3h[off] = bf16_rne(x3);
    }
}

// ---------------- K1: rank-1 scores + packed bf16 split (w/ prefetch) ----------------
// ent blocks [0,2048), rel blocks [2048,2111). Fold-reduction: 9 f32 shuffles.
__global__ __launch_bounds__(256) void ss_kernel(
    const float* __restrict__ ent, const float* __restrict__ relm,
    const float* __restrict__ U8, const double* __restrict__ u0,
    const float* __restrict__ V8, const double* __restrict__ v0,
    float* __restrict__ SS, double* __restrict__ ssrc0, unsigned short* __restrict__ apk,
    float* __restrict__ SSR, double* __restrict__ sr0, unsigned short* __restrict__ rpk)
{
    const int tid = threadIdx.x;
    const int l = tid & 63;
    const int el = l & 31;
    const int q2 = l >> 5;

    const bool isent = blockIdx.x < 2048;
    const float* X = isent ? ent : relm;
    const float* U8v = isent ? U8 : V8;
    const double* u0v = isent ? u0 : v0;
    float* SSout = isent ? SS : SSR;
    double* s0out = isent ? ssrc0 : sr0;
    unsigned short* Xpk = isent ? apk : rpk;
    const int N = isent ? N_ENT : N_REL;
    const int wave0 = isent ? ((blockIdx.x * 256 + tid) >> 6)
                            : (((blockIdx.x - 2048) * 256 + tid) >> 6);
    const int nwaves = isent ? 8192 : 252;

    float uu[8][8];
    #pragma unroll
    for (int i = 0; i < 8; ++i) {
        float4 a4 = *(const float4*)(U8v + (el * 8 + i) * 8);
        float4 b4 = *(const float4*)(U8v + (el * 8 + i) * 8 + 4);
        uu[i][0] = a4.x; uu[i][1] = a4.y; uu[i][2] = a4.z; uu[i][3] = a4.w;
        uu[i][4] = b4.x; uu[i][5] = b4.y; uu[i][6] = b4.z; uu[i][7] = b4.w;
    }
    double ud[8];
    #pragma unroll
    for (int i = 0; i < 8; ++i) ud[i] = u0v[el * 8 + i];

    const int jout = ((el & 1) << 2) | (el & 2) | ((el >> 2) & 1);
    const int half = N / 2;

    int p = wave0;
    float4 x1, x2;
    if (p < half) {
        int n0 = p * 2 + q2;
        x1 = *(const float4*)(X + (size_t)n0 * 256 + el * 8);
        x2 = *(const float4*)(X + (size_t)n0 * 256 + el * 8 + 4);
    }
    for (; p < half; p += nwaves) {
        const int n = p * 2 + q2;
        const float4 cx1 = x1, cx2 = x2;
        const int np = p + nwaves;
        if (np < half) {
            int n1 = np * 2 + q2;
            x1 = *(const float4*)(X + (size_t)n1 * 256 + el * 8);
            x2 = *(const float4*)(X + (size_t)n1 * 256 + el * 8 + 4);
        }
        float xs[8] = {cx1.x, cx1.y, cx1.z, cx1.w, cx2.x, cx2.y, cx2.z, cx2.w};

        short8v ov;
        #pragma unroll
        for (int i = 0; i < 8; ++i) ov[i] = (short)bf16_rne(xs[i]);
        *(short8v*)(Xpk + pack_off(n, el * 8)) = ov;

        float pj[8] = {0.f, 0.f, 0.f, 0.f, 0.f, 0.f, 0.f, 0.f};
        double pd = 0.0;
        #pragma unroll
        for (int i = 0; i < 8; ++i) {
            #pragma unroll
            for (int j = 0; j < 8; ++j) pj[j] += xs[i] * uu[i][j];
            pd += (double)xs[i] * ud[i];
        }

        const bool b1 = (el & 1);
        float q[4];
        #pragma unroll
        for (int j = 0; j < 4; ++j) {
            float mine = b1 ? pj[j + 4] : pj[j];
            float send = b1 ? pj[j] : pj[j + 4];
            q[j] = mine + __shfl_xor(send, 1);
        }
        const bool b2 = (el & 2);
        float r2[2];
        #pragma unroll
        for (int j = 0; j < 2; ++j) {
            float mine = b2 ? q[j + 2] : q[j];
            float send = b2 ? q[j] : q[j + 2];
            r2[j] = mine + __shfl_xor(send, 2);
        }
        const bool b4 = (el & 4);
        {
            float mine = b4 ? r2[1] : r2[0];
            float send = b4 ? r2[0] : r2[1];
            r2[0] = mine + __shfl_xor(send, 4);
        }
        r2[0] += __shfl_xor(r2[0], 8);
        r2[0] += __shfl_xor(r2[0], 16);

        #pragma unroll
        for (int off = 1; off < 32; off <<= 1) pd += __shfl_xor(pd, off);

        if (el < 8) SSout[(size_t)n * 8 + jout] = r2[0];
        if (el == 0) s0out[n] = pd;
    }
}

// ---------------- K2: packed MFMA GEMM, B hi only, bf16 out (ent + rel) ----------------
__global__ __launch_bounds__(256, 4) void gemm_hi(
    const unsigned short* __restrict__ A1, const unsigned short* __restrict__ B1,
    unsigned short* __restrict__ C1, int M1, int nb1,
    const unsigned short* __restrict__ A2, const unsigned short* __restrict__ B2,
    unsigned short* __restrict__ C2, int M2)
{
    const int tid = threadIdx.x;
    const int l = tid & 63;
    const int w = tid >> 6;
    const int rl = l & 15;
    const int ql = l >> 4;

    const int b = blockIdx.x;
    const unsigned short* Apk = (b < nb1) ? A1 : A2;
    const unsigned short* Bh  = (b < nb1) ? B1 : B2;
    unsigned short* C         = (b < nb1) ? C1 : C2;
    const int M               = (b < nb1) ? M1 : M2;
    const int bm              = ((b < nb1) ? b : (b - nb1)) * 64;

    const unsigned short* ab = Apk + (size_t)(bm >> 4) * 4096 + l * 8;
    const unsigned short* bhb = Bh + (size_t)w * 16384 + l * 8;

    f32x4 acc[4][4];
    #pragma unroll
    for (int i = 0; i < 4; ++i)
        #pragma unroll
        for (int j = 0; j < 4; ++j) acc[i][j] = (f32x4){0.f, 0.f, 0.f, 0.f};

    #pragma unroll
    for (int ks = 0; ks < 8; ++ks) {
        short8v ah[4], bh[4];
        #pragma unroll
        for (int mf = 0; mf < 4; ++mf)
            ah[mf] = *(const short8v*)(ab + mf * 4096 + ks * 512);
        #pragma unroll
        for (int nf = 0; nf < 4; ++nf)
            bh[nf] = *(const short8v*)(bhb + nf * 4096 + ks * 512);
        #pragma unroll
        for (int mf = 0; mf < 4; ++mf)
            #pragma unroll
            for (int nf = 0; nf < 4; ++nf)
                acc[mf][nf] = __builtin_amdgcn_mfma_f32_16x16x32_bf16(ah[mf], bh[nf], acc[mf][nf], 0, 0, 0);
    }

    #pragma unroll
    for (int mf = 0; mf < 4; ++mf) {
        int row0 = bm + mf * 16 + ql * 4;
        #pragma unroll
        for (int nf = 0; nf < 4; ++nf) {
            int c = w * 64 + nf * 16 + rl;
            #pragma unroll
            for (int j = 0; j < 4; ++j) {
                int r = row0 + j;
                if (r < M)
                    C[(size_t)r * 256 + c] = bf16_rne(acc[mf][nf][j]);
            }
        }
    }
}

// ---------------- K3: fused top-k select + softmax + gather-aggregate ----------------
// 32 lanes per node, 8 nodes per block; no barriers (wls is intra-wave);
// 20-deep forced gather hoist via s_waitcnt asm fence.
__global__ __launch_bounds__(256, 3) void node_kernel(
    const int* __restrict__ src, const int* __restrict__ relid,
    const float* __restrict__ SS, const double* __restrict__ ssrc0,
    const float* __restrict__ SSR, const double* __restrict__ sr0,
    const unsigned short* __restrict__ emb_bf, const unsigned short* __restrict__ rel_bf,
    unsigned short* __restrict__ napk)
{
    __shared__ float wls[8][32][4];   // per-wave region: written+read by same wave

    const int tid = threadIdx.x;
    const int l = tid & 63;
    const int el = l & 31;
    const int hb = l & 32;
    const int nib = tid >> 5;
    const int n = blockIdx.x * 8 + nib;

    const int sd_ = src[n * DEG + el];
    const int rd_ = relid[n * DEG + el];
    const double sc0 = ssrc0[sd_] + sr0[rd_];

    // rank by count (stable: lower index wins ties == jax.lax.top_k)
    int cnt = 0;
    #pragma unroll
    for (int j = 0; j < DEG; ++j) {
        double sj = __shfl(sc0, hb | j);
        cnt += (sj > sc0 || (sj == sc0 && j < el)) ? 1 : 0;
    }
    const bool sel = (cnt < TOPK);
    const unsigned mask = (unsigned)(__ballot(sel) >> hb);

    float scx = -1e30f, scy = -1e30f, scz = -1e30f, scw = -1e30f;
    if (sel) {
        float4 ssv = *(const float4*)(SS + (size_t)sd_ * 8);
        float4 srv = *(const float4*)(SSR + (size_t)rd_ * 8);
        float4 sdv = *(const float4*)(SS + (size_t)n * 8 + 4);
        scx = leaky(ssv.x + sdv.x + srv.x);
        scy = leaky(ssv.y + sdv.y + srv.y);
        scz = leaky(ssv.z + sdv.z + srv.z);
        scw = leaky(ssv.w + sdv.w + srv.w);
    }

    float mx = scx, my = scy, mz = scz, mw = scw;
    #pragma unroll
    for (int off = 1; off < 32; off <<= 1) {
        mx = fmaxf(mx, __shfl_xor(mx, off));
        my = fmaxf(my, __shfl_xor(my, off));
        mz = fmaxf(mz, __shfl_xor(mz, off));
        mw = fmaxf(mw, __shfl_xor(mw, off));
    }
    float ex = sel ? __expf(scx - mx) : 0.f;
    float ey = sel ? __expf(scy - my) : 0.f;
    float ez = sel ? __expf(scz - mz) : 0.f;
    float ew = sel ? __expf(scw - mw) : 0.f;
    float sx = ex, sy = ey, sz = ez, sw = ew;
    #pragma unroll
    for (int off = 1; off < 32; off <<= 1) {
        sx += __shfl_xor(sx, off);
        sy += __shfl_xor(sy, off);
        sz += __shfl_xor(sz, off);
        sw += __shfl_xor(sw, off);
    }

    if (sel) {
        float4 wv; wv.x = ex; wv.y = ey; wv.z = ez; wv.w = ew;
        *(float4*)&wls[nib][el][0] = wv;   // intra-wave: no barrier needed
    }

    // ---- aggregation: lane el covers dims el*8..el*8+7 (head h) of node n ----
    const int h = el >> 3;
    const float sh = h == 0 ? sx : h == 1 ? sy : h == 2 ? sz : sw;
    const float rsh = 1.f / sh;

    int lks[TOPK], sk[TOPK], rk[TOPK];
    unsigned mm = mask;
    #pragma unroll
    for (int k = 0; k < TOPK; ++k) {
        lks[k] = __builtin_ctz(mm);
        mm &= mm - 1;
        sk[k] = __shfl(sd_, hb | lks[k]);
        rk[k] = __shfl(rd_, hb | lks[k]);
    }

    // issue all 20 gathers, then fence so none can sink into the FMA loop
    short8v ev[TOPK], rv[TOPK];
    #pragma unroll
    for (int k = 0; k < TOPK; ++k)
        ev[k] = *(const short8v*)(emb_bf + (size_t)sk[k] * 256 + el * 8);
    #pragma unroll
    for (int k = 0; k < TOPK; ++k)
        rv[k] = *(const short8v*)(rel_bf + (size_t)rk[k] * 256 + el * 8);
    asm volatile("s_waitcnt vmcnt(0)" ::: "memory");

    float acc[8] = {0.f, 0.f, 0.f, 0.f, 0.f, 0.f, 0.f, 0.f};
    #pragma unroll
    for (int k = 0; k < TOPK; ++k) {
        float w = wls[nib][lks[k]][h] * rsh;
        #pragma unroll
        for (int j = 0; j < 8; ++j)
            acc[j] += w * (bf2f((unsigned short)ev[k][j]) + bf2f((unsigned short)rv[k][j]));
    }

    short8v ov;
    #pragma unroll
    for (int j = 0; j < 8; ++j) ov[j] = (short)bf16_rne(acc[j]);
    *(short8v*)(napk + pack_off(n, el * 8)) = ov;
}

// ---------------- K4: packed MFMA GEMM, B hi only, f32 tanh out ----------------
__global__ __launch_bounds__(256, 4) void gemm_out(
    const unsigned short* __restrict__ Apk, const unsigned short* __restrict__ Bpkh,
    float* __restrict__ Cout, int M)
{
    const int tid = threadIdx.x;
    const int l = tid & 63;
    const int w = tid >> 6;
    const int bm = blockIdx.x * 64;
    const int rl = l & 15;
    const int ql = l >> 4;

    const unsigned short* ab = Apk + (size_t)(bm >> 4) * 4096 + l * 8;
    const unsigned short* bhb = Bpkh + (size_t)w * 16384 + l * 8;

    f32x4 acc[4][4];
    #pragma unroll
    for (int i = 0; i < 4; ++i)
        #pragma unroll
        for (int j = 0; j < 4; ++j) acc[i][j] = (f32x4){0.f, 0.f, 0.f, 0.f};

    #pragma unroll
    for (int ks = 0; ks < 8; ++ks) {
        short8v ah[4], bh[4];
        #pragma unroll
        for (int mf = 0; mf < 4; ++mf)
            ah[mf] = *(const short8v*)(ab + mf * 4096 + ks * 512);
        #pragma unroll
        for (int nf = 0; nf < 4; ++nf)
            bh[nf] = *(const short8v*)(bhb + nf * 4096 + ks * 512);
        #pragma unroll
        for (int mf = 0; mf < 4; ++mf)
            #pragma unroll
            for (int nf = 0; nf < 4; ++nf)
                acc[mf][nf] = __builtin_amdgcn_mfma_f32_16x16x32_bf16(ah[mf], bh[nf], acc[mf][nf], 0, 0, 0);
    }

    #pragma unroll
    for (int mf = 0; mf < 4; ++mf) {
        int row0 = bm + mf * 16 + ql * 4;
        #pragma unroll
        for (int nf = 0; nf < 4; ++nf) {
            int c = w * 64 + nf * 16 + rl;
            #pragma unroll
            for (int j = 0; j < 4; ++j) {
                int r = row0 + j;
                if (r < M) {
                    float v = acc[mf][nf][j];
                    Cout[(size_t)r * 256 + c] = 1.f - 2.f / (__expf(2.f * v) + 1.f);
                }
            }
        }
    }
}

extern "C" void kernel_launch(void* const* d_in, const int* in_sizes, int n_in,
                              void* d_out, int out_size, void* d_ws, size_t ws_size,
                              hipStream_t stream) {
    const float* ent  = (const float*)d_in[0];
    const float* rel  = (const float*)d_in[1];
    const float* W    = (const float*)d_in[2];
    const float* W_r  = (const float*)d_in[3];
    const float* a    = (const float*)d_in[4];
    const float* nw   = (const float*)d_in[5];
    const int*   srcp = (const int*)d_in[6];
    const int*   ridp = (const int*)d_in[7];
    float* out = (float*)d_out;

    if (ws_size < WS_NEED) return;

    char* ws = (char*)d_ws;
    double* ssrc0 = (double*)(ws + OFF_SSRC0);
    double* sr0   = (double*)(ws + OFF_SR0);
    double* u0    = (double*)(ws + OFF_U0);
    double* v0    = (double*)(ws + OFF_V0);
    float*  SS    = (float*)(ws + OFF_SS);
    float*  SSR   = (float*)(ws + OFF_SSR);
    float*  U8    = (float*)(ws + OFF_U8);
    float*  V8    = (float*)(ws + OFF_V8);
    unsigned short* b1h = (unsigned short*)(ws + OFF_B1H);
    unsigned short* b2h = (unsigned short*)(ws + OFF_B2H);
    unsigned short* b3h = (unsigned short*)(ws + OFF_B3H);
    unsigned short* rpk = (unsigned short*)(ws + OFF_RPK);
    unsigned short* apk = (unsigned short*)(ws + OFF_EAH);
    unsigned short* embbf = (unsigned short*)(ws + OFF_EMBBF);
    unsigned short* relbf = (unsigned short*)(ws + OFF_RELBF);
    unsigned short* napk = apk;   // neigh-packed aliases ent-packed (dead after gemm_hi)

    setup_kernel<<<258, 256, 0, stream>>>(W, W_r, a, nw, U8, u0, V8, v0,
                                          b1h, b2h, b3h);
    ss_kernel<<<2111, 256, 0, stream>>>(ent, rel, U8, u0, V8, v0,
                                        SS, ssrc0, apk, SSR, sr0, rpk);
    gemm_hi<<<790, 256, 0, stream>>>(apk, b1h, embbf, N_ENT, 782,
                                     rpk, b3h, relbf, N_REL);
    node_kernel<<<6250, 256, 0, stream>>>(srcp, ridp, SS, ssrc0, SSR, sr0,
                                          embbf, relbf, napk);
    gemm_out<<<782, 256, 0, stream>>>(napk, b2h, out, N_ENT);
}

// Round 13
// 146.317 us; speedup vs baseline: 1.3508x; 1.0039x over previous
//
#include <hip/hip_runtime.h>
#include <math.h>

#define N_ENT 50000
#define N_REL 500
#define DEG 32
#define TOPK 10
#define H_DIM 256
#define N_HEADS 4
#define HEAD_DIM 64

typedef __attribute__((ext_vector_type(8))) short short8v;
typedef __attribute__((ext_vector_type(4))) float f32x4;

// ---------------- workspace layout (bytes) ----------------
constexpr size_t OFF_SSRC0 = 0;                      // f64 [N_ENT]
constexpr size_t OFF_SR0   = 400000;                 // f64 [N_REL]
constexpr size_t OFF_U0    = 404000;                 // f64 [256]
constexpr size_t OFF_V0    = 406048;                 // f64 [256]
constexpr size_t OFF_SS    = 408096;                 // f32 [N_ENT][8]
constexpr size_t OFF_SSR   = 2008096;                // f32 [N_REL][8] (cols 0..3 = sr4)
constexpr size_t OFF_U8    = 2024096;                // f32 [256][8]
constexpr size_t OFF_V8    = 2032288;                // f32 [256][8]
constexpr size_t OFF_B1H   = 2040480;                // bf16 packed 131072 B each
constexpr size_t OFF_B2H   = 2302624;
constexpr size_t OFF_B3H   = 2564768;
constexpr size_t OFF_RPK   = 2826912;                // bf16 packed rel rows (512) 262144 B
constexpr size_t OFF_EAH   = 3089056;                // bf16 packed A (ent; later neigh) 25,624,576 B
constexpr size_t OFF_EMBBF = 28713632;               // bf16 [N_ENT][256] emb_t (row-major)
constexpr size_t OFF_RELBF = 54313632;               // bf16 [N_REL][256]
constexpr size_t WS_NEED   = 54569632;               // ~52 MB

__device__ __forceinline__ float leaky(float x) { return x >= 0.f ? x : 0.2f * x; }

__device__ __forceinline__ unsigned short bf16_rne(float x) {
    unsigned int u = __float_as_uint(x);
    unsigned int r = u + 0x7fffu + ((u >> 16) & 1u);
    return (unsigned short)(r >> 16);
}
__device__ __forceinline__ float bf2f(unsigned short x) {
    return __uint_as_float((unsigned)x << 16);
}

// MFMA-fragment pack offset for element (row, d) of a [R][256] bf16 matrix.
__device__ __forceinline__ size_t pack_off(int row, int d) {
    return ((size_t)(row >> 4) * 8 + (d >> 5)) * 512 +
           (((d >> 3) & 3) * 16 + (row & 15)) * 8 + (d & 7);
}

// ---------------- K0: setup (U/V vectors | B splits) ----------------
__global__ __launch_bounds__(256) void setup_kernel(
    const float* __restrict__ W, const float* __restrict__ W_r,
    const float* __restrict__ a, const float* __restrict__ nw,
    float* __restrict__ U8, double* __restrict__ u0,
    float* __restrict__ V8, double* __restrict__ v0,
    unsigned short* __restrict__ b1h, unsigned short* __restrict__ b2h,
    unsigned short* __restrict__ b3h)
{
    const int bid = blockIdx.x;
    const int tid = threadIdx.x;
    if (bid == 0) {
        int d = tid;
        #pragma unroll
        for (int h = 0; h < N_HEADS; ++h) {
            float ss = 0.f, sd = 0.f;
            #pragma unroll
            for (int e = 0; e < HEAD_DIM; ++e) {
                float w = W[h * 16384 + d * 64 + e];
                ss += w * a[h * 192 + e];
                sd += w * a[h * 192 + 64 + e];
            }
            U8[d * 8 + h] = ss;
            U8[d * 8 + 4 + h] = sd;
        }
        double s0 = 0.0;
        #pragma unroll
        for (int e = 0; e < HEAD_DIM; ++e)
            s0 += (double)W[d * 64 + e] * (double)a[e];
        u0[d] = s0;
    } else if (bid == 1) {
        int d = tid;
        #pragma unroll
        for (int h = 0; h < N_HEADS; ++h) {
            float sv = 0.f;
            #pragma unroll
            for (int e = 0; e < HEAD_DIM; ++e)
                sv += W_r[h * 16384 + d * 64 + e] * a[h * 192 + 128 + e];
            V8[d * 8 + h] = sv;
            V8[d * 8 + 4 + h] = 0.f;
        }
        double s0 = 0.0;
        #pragma unroll
        for (int e = 0; e < HEAD_DIM; ++e)
            s0 += (double)W_r[d * 64 + e] * (double)a[128 + e];
        v0[d] = s0;
    } else {
        int n = bid - 2;     // output col
        int k = tid;         // inner dim
        int h = n >> 6, e = n & 63;
        float x1 = W[h * 16384 + k * 64 + e];
        float x2 = nw[k * 256 + n];
        float x3 = W_r[h * 16384 + k * 64 + e];
        size_t off = pack_off(n, k);
        b1h[off] = bf16_rne(x1);
        b2h[off] = bf16_rne(x2);
        b3h[off] = bf16_rne(x3);
    }
}

// ---------------- K1: rank-1 scores + packed bf16 split (w/ prefetch) ----------------
// ent blocks [0,2048), rel blocks [2048,2111). Fold-reduction: 9 f32 shuffles.
__global__ __launch_bounds__(256) void ss_kernel(
    const float* __restrict__ ent, const float* __restrict__ relm,
    const float* __restrict__ U8, const double* __restrict__ u0,
    const float* __restrict__ V8, const double* __restrict__ v0,
    float* __restrict__ SS, double* __restrict__ ssrc0, unsigned short* __restrict__ apk,
    float* __restrict__ SSR, double* __restrict__ sr0, unsigned short* __restrict__ rpk)
{
    const int tid = threadIdx.x;
    const int l = tid & 63;
    const int el = l & 31;
    const int q2 = l >> 5;

    const bool isent = blockIdx.x < 2048;
    const float* X = isent ? ent : relm;
    const float* U8v = isent ? U8 : V8;
    const double* u0v = isent ? u0 : v0;
    float* SSout = isent ? SS : SSR;
    double* s0out = isent ? ssrc0 : sr0;
    unsigned short* Xpk = isent ? apk : rpk;
    const int N = isent ? N_ENT : N_REL;
    const int wave0 = isent ? ((blockIdx.x * 256 + tid) >> 6)
                            : (((blockIdx.x - 2048) * 256 + tid) >> 6);
    const int nwaves = isent ? 8192 : 252;

    float uu[8][8];
    #pragma unroll
    for (int i = 0; i < 8; ++i) {
        float4 a4 = *(const float4*)(U8v + (el * 8 + i) * 8);
        float4 b4 = *(const float4*)(U8v + (el * 8 + i) * 8 + 4);
        uu[i][0] = a4.x; uu[i][1] = a4.y; uu[i][2] = a4.z; uu[i][3] = a4.w;
        uu[i][4] = b4.x; uu[i][5] = b4.y; uu[i][6] = b4.z; uu[i][7] = b4.w;
    }
    double ud[8];
    #pragma unroll
    for (int i = 0; i < 8; ++i) ud[i] = u0v[el * 8 + i];

    const int jout = ((el & 1) << 2) | (el & 2) | ((el >> 2) & 1);
    const int half = N / 2;

    int p = wave0;
    float4 x1, x2;
    if (p < half) {
        int n0 = p * 2 + q2;
        x1 = *(const float4*)(X + (size_t)n0 * 256 + el * 8);
        x2 = *(const float4*)(X + (size_t)n0 * 256 + el * 8 + 4);
    }
    for (; p < half; p += nwaves) {
        const int n = p * 2 + q2;
        const float4 cx1 = x1, cx2 = x2;
        const int np = p + nwaves;
        if (np < half) {
            int n1 = np * 2 + q2;
            x1 = *(const float4*)(X + (size_t)n1 * 256 + el * 8);
            x2 = *(const float4*)(X + (size_t)n1 * 256 + el * 8 + 4);
        }
        float xs[8] = {cx1.x, cx1.y, cx1.z, cx1.w, cx2.x, cx2.y, cx2.z, cx2.w};

        short8v ov;
        #pragma unroll
        for (int i = 0; i < 8; ++i) ov[i] = (short)bf16_rne(xs[i]);
        *(short8v*)(Xpk + pack_off(n, el * 8)) = ov;

        float pj[8] = {0.f, 0.f, 0.f, 0.f, 0.f, 0.f, 0.f, 0.f};
        double pd = 0.0;
        #pragma unroll
        for (int i = 0; i < 8; ++i) {
            #pragma unroll
            for (int j = 0; j < 8; ++j) pj[j] += xs[i] * uu[i][j];
            pd += (double)xs[i] * ud[i];
        }

        const bool b1 = (el & 1);
        float q[4];
        #pragma unroll
        for (int j = 0; j < 4; ++j) {
            float mine = b1 ? pj[j + 4] : pj[j];
            float send = b1 ? pj[j] : pj[j + 4];
            q[j] = mine + __shfl_xor(send, 1);
        }
        const bool b2 = (el & 2);
        float r2[2];
        #pragma unroll
        for (int j = 0; j < 2; ++j) {
            float mine = b2 ? q[j + 2] : q[j];
            float send = b2 ? q[j] : q[j + 2];
            r2[j] = mine + __shfl_xor(send, 2);
        }
        const bool b4 = (el & 4);
        {
            float mine = b4 ? r2[1] : r2[0];
            float send = b4 ? r2[0] : r2[1];
            r2[0] = mine + __shfl_xor(send, 4);
        }
        r2[0] += __shfl_xor(r2[0], 8);
        r2[0] += __shfl_xor(r2[0], 16);

        #pragma unroll
        for (int off = 1; off < 32; off <<= 1) pd += __shfl_xor(pd, off);

        if (el < 8) SSout[(size_t)n * 8 + jout] = r2[0];
        if (el == 0) s0out[n] = pd;
    }
}

// ---------------- K2: packed MFMA GEMM, B hi only, bf16 out (ent + rel) ----------------
__global__ __launch_bounds__(256, 4) void gemm_hi(
    const unsigned short* __restrict__ A1, const unsigned short* __restrict__ B1,
    unsigned short* __restrict__ C1, int M1, int nb1,
    const unsigned short* __restrict__ A2, const unsigned short* __restrict__ B2,
    unsigned short* __restrict__ C2, int M2)
{
    const int tid = threadIdx.x;
    const int l = tid & 63;
    const int w = tid >> 6;
    const int rl = l & 15;
    const int ql = l >> 4;

    const int b = blockIdx.x;
    const unsigned short* Apk = (b < nb1) ? A1 : A2;
    const unsigned short* Bh  = (b < nb1) ? B1 : B2;
    unsigned short* C         = (b < nb1) ? C1 : C2;
    const int M               = (b < nb1) ? M1 : M2;
    const int bm              = ((b < nb1) ? b : (b - nb1)) * 64;

    const unsigned short* ab = Apk + (size_t)(bm >> 4) * 4096 + l * 8;
    const unsigned short* bhb = Bh + (size_t)w * 16384 + l * 8;

    f32x4 acc[4][4];
    #pragma unroll
    for (int i = 0; i < 4; ++i)
        #pragma unroll
        for (int j = 0; j < 4; ++j) acc[i][j] = (f32x4){0.f, 0.f, 0.f, 0.f};

    #pragma unroll
    for (int ks = 0; ks < 8; ++ks) {
        short8v ah[4], bh[4];
        #pragma unroll
        for (int mf = 0; mf < 4; ++mf)
            ah[mf] = *(const short8v*)(ab + mf * 4096 + ks * 512);
        #pragma unroll
        for (int nf = 0; nf < 4; ++nf)
            bh[nf] = *(const short8v*)(bhb + nf * 4096 + ks * 512);
        #pragma unroll
        for (int mf = 0; mf < 4; ++mf)
            #pragma unroll
            for (int nf = 0; nf < 4; ++nf)
                acc[mf][nf] = __builtin_amdgcn_mfma_f32_16x16x32_bf16(ah[mf], bh[nf], acc[mf][nf], 0, 0, 0);
    }

    #pragma unroll
    for (int mf = 0; mf < 4; ++mf) {
        int row0 = bm + mf * 16 + ql * 4;
        #pragma unroll
        for (int nf = 0; nf < 4; ++nf) {
            int c = w * 64 + nf * 16 + rl;
            #pragma unroll
            for (int j = 0; j < 4; ++j) {
                int r = row0 + j;
                if (r < M)
                    C[(size_t)r * 256 + c] = bf16_rne(acc[mf][nf][j]);
            }
        }
    }
}

// ---------------- K3: fused top-k select + softmax + gather-aggregate ----------------
// 32 lanes per node, 8 nodes per block; no barriers (all LDS handoff is intra-wave:
// DS ops execute in wave program order); rank via LDS broadcast; no-max softmax;
// fold-reduced sums; 20-deep fenced gather hoist.
__global__ __launch_bounds__(256, 3) void node_kernel(
    const int* __restrict__ src, const int* __restrict__ relid,
    const float* __restrict__ SS, const double* __restrict__ ssrc0,
    const float* __restrict__ SSR, const double* __restrict__ sr0,
    const unsigned short* __restrict__ emb_bf, const unsigned short* __restrict__ rel_bf,
    unsigned short* __restrict__ napk)
{
    __shared__ double scs[8][33];        // padded row (264 B) to decorrelate banks
    __shared__ unsigned idsS[8][12];
    __shared__ float wtsS[8][10][4];
    __shared__ float sumsS[8][4];

    const int tid = threadIdx.x;
    const int l = tid & 63;
    const int el = l & 31;
    const int hb = l & 32;
    const int nib = tid >> 5;
    const int n = blockIdx.x * 8 + nib;

    const int sd_ = src[n * DEG + el];
    const int rd_ = relid[n * DEG + el];
    const double sc0 = ssrc0[sd_] + sr0[rd_];
    scs[nib][el] = sc0;

    // rank by count via LDS broadcast (stable: lower index wins ties == jax.lax.top_k)
    int cnt = 0;
    #pragma unroll
    for (int j = 0; j < DEG; ++j) {
        double sj = scs[nib][j];
        cnt += (sj > sc0 || (sj == sc0 && j < el)) ? 1 : 0;
    }
    const bool sel = (cnt < TOPK);
    const unsigned mask = (unsigned)(__ballot(sel) >> hb);
    const int pos = __popc(mask & ((1u << el) - 1u));

    // raw exp weights (no max-subtraction: scores are O(+-3), exp is safe;
    // softmax is shift-invariant so the normalized result is identical)
    float ex = 0.f, ey = 0.f, ez = 0.f, ew = 0.f;
    if (sel) {
        float4 ssv = *(const float4*)(SS + (size_t)sd_ * 8);
        float4 srv = *(const float4*)(SSR + (size_t)rd_ * 8);
        float4 sdv = *(const float4*)(SS + (size_t)n * 8 + 4);
        ex = __expf(leaky(ssv.x + sdv.x + srv.x));
        ey = __expf(leaky(ssv.y + sdv.y + srv.y));
        ez = __expf(leaky(ssv.z + sdv.z + srv.z));
        ew = __expf(leaky(ssv.w + sdv.w + srv.w));
        idsS[nib][pos] = (unsigned)sd_ | ((unsigned)rd_ << 16);
        float4 wv; wv.x = ex; wv.y = ey; wv.z = ez; wv.w = ew;
        *(float4*)&wtsS[nib][pos][0] = wv;
    }

    // fold-reduce the 4 head sums over 32 lanes: 6 shuffles total
    float p0, p1;
    {
        const bool b1 = (el & 1);
        float m0 = b1 ? ez : ex, s0 = b1 ? ex : ez;
        float m1 = b1 ? ew : ey, s1 = b1 ? ey : ew;
        p0 = m0 + __shfl_xor(s0, 1);   // even: h0 pair-sum, odd: h2
        p1 = m1 + __shfl_xor(s1, 1);   // even: h1, odd: h3
    }
    float qsum;
    {
        const bool b2 = (el & 2);
        float m = b2 ? p1 : p0, s = b2 ? p0 : p1;
        qsum = m + __shfl_xor(s, 2);   // lane el&3 owns head ((el&1)<<1)|((el>>1)&1)
    }
    qsum += __shfl_xor(qsum, 4);
    qsum += __shfl_xor(qsum, 8);
    qsum += __shfl_xor(qsum, 16);
    if (el < 4) sumsS[nib][((el & 1) << 1) | ((el >> 1) & 1)] = qsum;

    // ---- aggregation: lane el covers dims el*8..el*8+7 (head h) of node n ----
    const int h = el >> 3;

    int skA[TOPK], rkA[TOPK];
    #pragma unroll
    for (int k = 0; k < TOPK; ++k) {
        unsigned idk = idsS[nib][k];   // broadcast read per half-wave
        skA[k] = (int)(idk & 0xFFFFu);
        rkA[k] = (int)(idk >> 16);
    }

    // issue all 20 gathers, then fence so none can sink into the FMA loop
    short8v ev[TOPK], rv[TOPK];
    #pragma unroll
    for (int k = 0; k < TOPK; ++k)
        ev[k] = *(const short8v*)(emb_bf + (size_t)skA[k] * 256 + el * 8);
    #pragma unroll
    for (int k = 0; k < TOPK; ++k)
        rv[k] = *(const short8v*)(rel_bf + (size_t)rkA[k] * 256 + el * 8);
    asm volatile("s_waitcnt vmcnt(0)" ::: "memory");

    const float rsh = 1.f / sumsS[nib][h];
    float acc[8] = {0.f, 0.f, 0.f, 0.f, 0.f, 0.f, 0.f, 0.f};
    #pragma unroll
    for (int k = 0; k < TOPK; ++k) {
        float w = wtsS[nib][k][h] * rsh;
        #pragma unroll
        for (int j = 0; j < 8; ++j)
            acc[j] += w * (bf2f((unsigned short)ev[k][j]) + bf2f((unsigned short)rv[k][j]));
    }

    short8v ov;
    #pragma unroll
    for (int j = 0; j < 8; ++j) ov[j] = (short)bf16_rne(acc[j]);
    *(short8v*)(napk + pack_off(n, el * 8)) = ov;
}

// ---------------- K4: packed MFMA GEMM, B hi only, f32 tanh out ----------------
__global__ __launch_bounds__(256, 4) void gemm_out(
    const unsigned short* __restrict__ Apk, const unsigned short* __restrict__ Bpkh,
    float* __restrict__ Cout, int M)
{
    const int tid = threadIdx.x;
    const int l = tid & 63;
    const int w = tid >> 6;
    const int bm = blockIdx.x * 64;
    const int rl = l & 15;
    const int ql = l >> 4;

    const unsigned short* ab = Apk + (size_t)(bm >> 4) * 4096 + l * 8;
    const unsigned short* bhb = Bpkh + (size_t)w * 16384 + l * 8;

    f32x4 acc[4][4];
    #pragma unroll
    for (int i = 0; i < 4; ++i)
        #pragma unroll
        for (int j = 0; j < 4; ++j) acc[i][j] = (f32x4){0.f, 0.f, 0.f, 0.f};

    #pragma unroll
    for (int ks = 0; ks < 8; ++ks) {
        short8v ah[4], bh[4];
        #pragma unroll
        for (int mf = 0; mf < 4; ++mf)
            ah[mf] = *(const short8v*)(ab + mf * 4096 + ks * 512);
        #pragma unroll
        for (int nf = 0; nf < 4; ++nf)
            bh[nf] = *(const short8v*)(bhb + nf * 4096 + ks * 512);
        #pragma unroll
        for (int mf = 0; mf < 4; ++mf)
            #pragma unroll
            for (int nf = 0; nf < 4; ++nf)
                acc[mf][nf] = __builtin_amdgcn_mfma_f32_16x16x32_bf16(ah[mf], bh[nf], acc[mf][nf], 0, 0, 0);
    }

    #pragma unroll
    for (int mf = 0; mf < 4; ++mf) {
        int row0 = bm + mf * 16 + ql * 4;
        #pragma unroll
        for (int nf = 0; nf < 4; ++nf) {
            int c = w * 64 + nf * 16 + rl;
            #pragma unroll
            for (int j = 0; j < 4; ++j) {
                int r = row0 + j;
                if (r < M) {
                    float v = acc[mf][nf][j];
                    Cout[(size_t)r * 256 + c] = 1.f - 2.f / (__expf(2.f * v) + 1.f);
                }
            }
        }
    }
}

extern "C" void kernel_launch(void* const* d_in, const int* in_sizes, int n_in,
                              void* d_out, int out_size, void* d_ws, size_t ws_size,
                              hipStream_t stream) {
    const float* ent  = (const float*)d_in[0];
    const float* rel  = (const float*)d_in[1];
    const float* W    = (const float*)d_in[2];
    const float* W_r  = (const float*)d_in[3];
    const float* a    = (const float*)d_in[4];
    const float* nw   = (const float*)d_in[5];
    const int*   srcp = (const int*)d_in[6];
    const int*   ridp = (const int*)d_in[7];
    float* out = (float*)d_out;

    if (ws_size < WS_NEED) return;

    char* ws = (char*)d_ws;
    double* ssrc0 = (double*)(ws + OFF_SSRC0);
    double* sr0   = (double*)(ws + OFF_SR0);
    double* u0    = (double*)(ws + OFF_U0);
    double* v0    = (double*)(ws + OFF_V0);
    float*  SS    = (float*)(ws + OFF_SS);
    float*  SSR   = (float*)(ws + OFF_SSR);
    float*  U8    = (float*)(ws + OFF_U8);
    float*  V8    = (float*)(ws + OFF_V8);
    unsigned short* b1h = (unsigned short*)(ws + OFF_B1H);
    unsigned short* b2h = (unsigned short*)(ws + OFF_B2H);
    unsigned short* b3h = (unsigned short*)(ws + OFF_B3H);
    unsigned short* rpk = (unsigned short*)(ws + OFF_RPK);
    unsigned short* apk = (unsigned short*)(ws + OFF_EAH);
    unsigned short* embbf = (unsigned short*)(ws + OFF_EMBBF);
    unsigned short* relbf = (unsigned short*)(ws + OFF_RELBF);
    unsigned short* napk = apk;   // neigh-packed aliases ent-packed (dead after gemm_hi)

    setup_kernel<<<258, 256, 0, stream>>>(W, W_r, a, nw, U8, u0, V8, v0,
                                          b1h, b2h, b3h);
    ss_kernel<<<2111, 256, 0, stream>>>(ent, rel, U8, u0, V8, v0,
                                        SS, ssrc0, apk, SSR, sr0, rpk);
    gemm_hi<<<790, 256, 0, stream>>>(apk, b1h, embbf, N_ENT, 782,
                                     rpk, b3h, relbf, N_REL);
    node_kernel<<<6250, 256, 0, stream>>>(srcp, ridp, SS, ssrc0, SSR, sr0,
                                          embbf, relbf, napk);
    gemm_out<<<782, 256, 0, stream>>>(napk, b2h, out, N_ENT);
}

// Round 14
// 140.704 us; speedup vs baseline: 1.4046x; 1.0399x over previous
//
#include <hip/hip_runtime.h>
#include <math.h>

#define N_ENT 50000
#define N_REL 500
#define DEG 32
#define TOPK 10
#define H_DIM 256
#define N_HEADS 4
#define HEAD_DIM 64

typedef __attribute__((ext_vector_type(8))) short short8v;
typedef __attribute__((ext_vector_type(4))) float f32x4;

// ---------------- workspace layout (bytes) ----------------
constexpr size_t OFF_SSRC0 = 0;                      // f64 [N_ENT]
constexpr size_t OFF_SR0   = 400000;                 // f64 [N_REL]
constexpr size_t OFF_U0    = 404000;                 // f64 [256]
constexpr size_t OFF_V0    = 406048;                 // f64 [256]
constexpr size_t OFF_SS    = 408096;                 // f32 [N_ENT][8]
constexpr size_t OFF_SSR   = 2008096;                // f32 [N_REL][8]
constexpr size_t OFF_U8    = 2024096;                // f32 [256][8]
constexpr size_t OFF_V8    = 2032288;                // f32 [256][8]
constexpr size_t OFF_B1H   = 2040480;                // bf16 packed 131072 B each
constexpr size_t OFF_B2H   = 2302624;
constexpr size_t OFF_B3H   = 2564768;
constexpr size_t OFF_RPK   = 2826912;                // bf16 row-major rel rows [512][256]
constexpr size_t OFF_EAH   = 3089056;                // bf16 row-major A (ent; later neigh) [50048][256]
constexpr size_t OFF_EMBBF = 28713632;               // bf16 [N_ENT][256] emb_t (row-major)
constexpr size_t OFF_RELBF = 54313632;               // bf16 [N_REL][256]
constexpr size_t WS_NEED   = 54569632;               // ~52 MB

__device__ __forceinline__ float leaky(float x) { return x >= 0.f ? x : 0.2f * x; }

__device__ __forceinline__ unsigned short bf16_rne(float x) {
    unsigned int u = __float_as_uint(x);
    unsigned int r = u + 0x7fffu + ((u >> 16) & 1u);
    return (unsigned short)(r >> 16);
}
__device__ __forceinline__ float bf2f(unsigned short x) {
    return __uint_as_float((unsigned)x << 16);
}

// B-side MFMA-fragment pack offset (unchanged; B tables are tiny and written once)
__device__ __forceinline__ size_t pack_off(int row, int d) {
    return ((size_t)(row >> 4) * 8 + (d >> 5)) * 512 +
           (((d >> 3) & 3) * 16 + (row & 15)) * 8 + (d & 7);
}

// ---------------- K0: setup (U/V vectors | B splits) ----------------
__global__ __launch_bounds__(256) void setup_kernel(
    const float* __restrict__ W, const float* __restrict__ W_r,
    const float* __restrict__ a, const float* __restrict__ nw,
    float* __restrict__ U8, double* __restrict__ u0,
    float* __restrict__ V8, double* __restrict__ v0,
    unsigned short* __restrict__ b1h, unsigned short* __restrict__ b2h,
    unsigned short* __restrict__ b3h)
{
    const int bid = blockIdx.x;
    const int tid = threadIdx.x;
    if (bid == 0) {
        int d = tid;
        #pragma unroll
        for (int h = 0; h < N_HEADS; ++h) {
            float ss = 0.f, sd = 0.f;
            #pragma unroll
            for (int e = 0; e < HEAD_DIM; ++e) {
                float w = W[h * 16384 + d * 64 + e];
                ss += w * a[h * 192 + e];
                sd += w * a[h * 192 + 64 + e];
            }
            U8[d * 8 + h] = ss;
            U8[d * 8 + 4 + h] = sd;
        }
        double s0 = 0.0;
        #pragma unroll
        for (int e = 0; e < HEAD_DIM; ++e)
            s0 += (double)W[d * 64 + e] * (double)a[e];
        u0[d] = s0;
    } else if (bid == 1) {
        int d = tid;
        #pragma unroll
        for (int h = 0; h < N_HEADS; ++h) {
            float sv = 0.f;
            #pragma unroll
            for (int e = 0; e < HEAD_DIM; ++e)
                sv += W_r[h * 16384 + d * 64 + e] * a[h * 192 + 128 + e];
            V8[d * 8 + h] = sv;
            V8[d * 8 + 4 + h] = 0.f;
        }
        double s0 = 0.0;
        #pragma unroll
        for (int e = 0; e < HEAD_DIM; ++e)
            s0 += (double)W_r[d * 64 + e] * (double)a[128 + e];
        v0[d] = s0;
    } else {
        int n = bid - 2;     // output col
        int k = tid;         // inner dim
        int h = n >> 6, e = n & 63;
        float x1 = W[h * 16384 + k * 64 + e];
        float x2 = nw[k * 256 + n];
        float x3 = W_r[h * 16384 + k * 64 + e];
        size_t off = pack_off(n, k);
        b1h[off] = bf16_rne(x1);
        b2h[off] = bf16_rne(x2);
        b3h[off] = bf16_rne(x3);
    }
}

// ---------------- K1: rank-1 scores + row-major bf16 split (w/ prefetch) ----------------
__global__ __launch_bounds__(256) void ss_kernel(
    const float* __restrict__ ent, const float* __restrict__ relm,
    const float* __restrict__ U8, const double* __restrict__ u0,
    const float* __restrict__ V8, const double* __restrict__ v0,
    float* __restrict__ SS, double* __restrict__ ssrc0, unsigned short* __restrict__ apk,
    float* __restrict__ SSR, double* __restrict__ sr0, unsigned short* __restrict__ rpk)
{
    const int tid = threadIdx.x;
    const int l = tid & 63;
    const int el = l & 31;
    const int q2 = l >> 5;

    const bool isent = blockIdx.x < 2048;
    const float* X = isent ? ent : relm;
    const float* U8v = isent ? U8 : V8;
    const double* u0v = isent ? u0 : v0;
    float* SSout = isent ? SS : SSR;
    double* s0out = isent ? ssrc0 : sr0;
    unsigned short* Xpk = isent ? apk : rpk;
    const int N = isent ? N_ENT : N_REL;
    const int wave0 = isent ? ((blockIdx.x * 256 + tid) >> 6)
                            : (((blockIdx.x - 2048) * 256 + tid) >> 6);
    const int nwaves = isent ? 8192 : 252;

    float uu[8][8];
    #pragma unroll
    for (int i = 0; i < 8; ++i) {
        float4 a4 = *(const float4*)(U8v + (el * 8 + i) * 8);
        float4 b4 = *(const float4*)(U8v + (el * 8 + i) * 8 + 4);
        uu[i][0] = a4.x; uu[i][1] = a4.y; uu[i][2] = a4.z; uu[i][3] = a4.w;
        uu[i][4] = b4.x; uu[i][5] = b4.y; uu[i][6] = b4.z; uu[i][7] = b4.w;
    }
    double ud[8];
    #pragma unroll
    for (int i = 0; i < 8; ++i) ud[i] = u0v[el * 8 + i];

    const int jout = ((el & 1) << 2) | (el & 2) | ((el >> 2) & 1);
    const int half = N / 2;

    int p = wave0;
    float4 x1, x2;
    if (p < half) {
        int n0 = p * 2 + q2;
        x1 = *(const float4*)(X + (size_t)n0 * 256 + el * 8);
        x2 = *(const float4*)(X + (size_t)n0 * 256 + el * 8 + 4);
    }
    for (; p < half; p += nwaves) {
        const int n = p * 2 + q2;
        const float4 cx1 = x1, cx2 = x2;
        const int np = p + nwaves;
        if (np < half) {
            int n1 = np * 2 + q2;
            x1 = *(const float4*)(X + (size_t)n1 * 256 + el * 8);
            x2 = *(const float4*)(X + (size_t)n1 * 256 + el * 8 + 4);
        }
        float xs[8] = {cx1.x, cx1.y, cx1.z, cx1.w, cx2.x, cx2.y, cx2.z, cx2.w};

        short8v ov;
        #pragma unroll
        for (int i = 0; i < 8; ++i) ov[i] = (short)bf16_rne(xs[i]);
        *(short8v*)(Xpk + (size_t)n * 256 + el * 8) = ov;   // row-major: coalesced

        float pj[8] = {0.f, 0.f, 0.f, 0.f, 0.f, 0.f, 0.f, 0.f};
        double pd = 0.0;
        #pragma unroll
        for (int i = 0; i < 8; ++i) {
            #pragma unroll
            for (int j = 0; j < 8; ++j) pj[j] += xs[i] * uu[i][j];
            pd += (double)xs[i] * ud[i];
        }

        const bool b1 = (el & 1);
        float q[4];
        #pragma unroll
        for (int j = 0; j < 4; ++j) {
            float mine = b1 ? pj[j + 4] : pj[j];
            float send = b1 ? pj[j] : pj[j + 4];
            q[j] = mine + __shfl_xor(send, 1);
        }
        const bool b2 = (el & 2);
        float r2[2];
        #pragma unroll
        for (int j = 0; j < 2; ++j) {
            float mine = b2 ? q[j + 2] : q[j];
            float send = b2 ? q[j] : q[j + 2];
            r2[j] = mine + __shfl_xor(send, 2);
        }
        const bool b4 = (el & 4);
        {
            float mine = b4 ? r2[1] : r2[0];
            float send = b4 ? r2[0] : r2[1];
            r2[0] = mine + __shfl_xor(send, 4);
        }
        r2[0] += __shfl_xor(r2[0], 8);
        r2[0] += __shfl_xor(r2[0], 16);

        #pragma unroll
        for (int off = 1; off < 32; off <<= 1) pd += __shfl_xor(pd, off);

        if (el < 8) SSout[(size_t)n * 8 + jout] = r2[0];
        if (el == 0) s0out[n] = pd;
    }
}

// ---------------- K2: MFMA GEMM, row-major A staged to LDS, B hi packed, bf16 out ----------------
__global__ __launch_bounds__(256, 4) void gemm_hi(
    const unsigned short* __restrict__ A1, const unsigned short* __restrict__ B1,
    unsigned short* __restrict__ C1, int M1, int nb1,
    const unsigned short* __restrict__ A2, const unsigned short* __restrict__ B2,
    unsigned short* __restrict__ C2, int M2)
{
    __shared__ unsigned short As[64][264];   // padded stride: b128 reads conflict-free

    const int tid = threadIdx.x;
    const int l = tid & 63;
    const int w = tid >> 6;
    const int rl = l & 15;
    const int ql = l >> 4;

    const int b = blockIdx.x;
    const unsigned short* A = (b < nb1) ? A1 : A2;
    const unsigned short* Bh = (b < nb1) ? B1 : B2;
    unsigned short* C       = (b < nb1) ? C1 : C2;
    const int M             = (b < nb1) ? M1 : M2;
    const int bm            = ((b < nb1) ? b : (b - nb1)) * 64;

    // stage 64x256 bf16 A-tile: linear coalesced global reads
    const unsigned short* Ag = A + (size_t)bm * 256;
    #pragma unroll
    for (int i = 0; i < 8; ++i) {
        int u = i * 256 + tid;          // 16B unit index within the 32KB tile
        short8v v = *(const short8v*)(Ag + (size_t)u * 8);
        *(short8v*)&As[u >> 5][(u & 31) * 8] = v;
    }
    __syncthreads();

    const unsigned short* bhb = Bh + (size_t)w * 16384 + l * 8;

    f32x4 acc[4][4];
    #pragma unroll
    for (int i = 0; i < 4; ++i)
        #pragma unroll
        for (int j = 0; j < 4; ++j) acc[i][j] = (f32x4){0.f, 0.f, 0.f, 0.f};

    #pragma unroll
    for (int ks = 0; ks < 8; ++ks) {
        short8v ah[4], bh[4];
        #pragma unroll
        for (int mf = 0; mf < 4; ++mf)
            ah[mf] = *(const short8v*)&As[mf * 16 + rl][ks * 32 + ql * 8];
        #pragma unroll
        for (int nf = 0; nf < 4; ++nf)
            bh[nf] = *(const short8v*)(bhb + nf * 4096 + ks * 512);
        #pragma unroll
        for (int mf = 0; mf < 4; ++mf)
            #pragma unroll
            for (int nf = 0; nf < 4; ++nf)
                acc[mf][nf] = __builtin_amdgcn_mfma_f32_16x16x32_bf16(ah[mf], bh[nf], acc[mf][nf], 0, 0, 0);
    }

    #pragma unroll
    for (int mf = 0; mf < 4; ++mf) {
        int row0 = bm + mf * 16 + ql * 4;
        #pragma unroll
        for (int nf = 0; nf < 4; ++nf) {
            int c = w * 64 + nf * 16 + rl;
            #pragma unroll
            for (int j = 0; j < 4; ++j) {
                int r = row0 + j;
                if (r < M)
                    C[(size_t)r * 256 + c] = bf16_rne(acc[mf][nf][j]);
            }
        }
    }
}

// ---------------- K3: fused top-k select + softmax + gather-aggregate ----------------
// 32 lanes per node, 8 nodes per block; no barriers (all LDS handoff intra-wave);
// rank via LDS broadcast; no-max softmax; fold-reduced sums; 20-deep fenced hoist.
__global__ __launch_bounds__(256, 3) void node_kernel(
    const int* __restrict__ src, const int* __restrict__ relid,
    const float* __restrict__ SS, const double* __restrict__ ssrc0,
    const float* __restrict__ SSR, const double* __restrict__ sr0,
    const unsigned short* __restrict__ emb_bf, const unsigned short* __restrict__ rel_bf,
    unsigned short* __restrict__ napk)
{
    __shared__ double scs[8][33];
    __shared__ unsigned idsS[8][12];
    __shared__ float wtsS[8][10][4];
    __shared__ float sumsS[8][4];

    const int tid = threadIdx.x;
    const int l = tid & 63;
    const int el = l & 31;
    const int hb = l & 32;
    const int nib = tid >> 5;
    const int n = blockIdx.x * 8 + nib;

    const int sd_ = src[n * DEG + el];
    const int rd_ = relid[n * DEG + el];
    const double sc0 = ssrc0[sd_] + sr0[rd_];
    scs[nib][el] = sc0;

    int cnt = 0;
    #pragma unroll
    for (int j = 0; j < DEG; ++j) {
        double sj = scs[nib][j];
        cnt += (sj > sc0 || (sj == sc0 && j < el)) ? 1 : 0;
    }
    const bool sel = (cnt < TOPK);
    const unsigned mask = (unsigned)(__ballot(sel) >> hb);
    const int pos = __popc(mask & ((1u << el) - 1u));

    float ex = 0.f, ey = 0.f, ez = 0.f, ew = 0.f;
    if (sel) {
        float4 ssv = *(const float4*)(SS + (size_t)sd_ * 8);
        float4 srv = *(const float4*)(SSR + (size_t)rd_ * 8);
        float4 sdv = *(const float4*)(SS + (size_t)n * 8 + 4);
        ex = __expf(leaky(ssv.x + sdv.x + srv.x));
        ey = __expf(leaky(ssv.y + sdv.y + srv.y));
        ez = __expf(leaky(ssv.z + sdv.z + srv.z));
        ew = __expf(leaky(ssv.w + sdv.w + srv.w));
        idsS[nib][pos] = (unsigned)sd_ | ((unsigned)rd_ << 16);
        float4 wv; wv.x = ex; wv.y = ey; wv.z = ez; wv.w = ew;
        *(float4*)&wtsS[nib][pos][0] = wv;
    }

    float p0, p1;
    {
        const bool b1 = (el & 1);
        float m0 = b1 ? ez : ex, s0 = b1 ? ex : ez;
        float m1 = b1 ? ew : ey, s1 = b1 ? ey : ew;
        p0 = m0 + __shfl_xor(s0, 1);
        p1 = m1 + __shfl_xor(s1, 1);
    }
    float qsum;
    {
        const bool b2 = (el & 2);
        float m = b2 ? p1 : p0, s = b2 ? p0 : p1;
        qsum = m + __shfl_xor(s, 2);
    }
    qsum += __shfl_xor(qsum, 4);
    qsum += __shfl_xor(qsum, 8);
    qsum += __shfl_xor(qsum, 16);
    if (el < 4) sumsS[nib][((el & 1) << 1) | ((el >> 1) & 1)] = qsum;

    const int h = el >> 3;

    int skA[TOPK], rkA[TOPK];
    #pragma unroll
    for (int k = 0; k < TOPK; ++k) {
        unsigned idk = idsS[nib][k];
        skA[k] = (int)(idk & 0xFFFFu);
        rkA[k] = (int)(idk >> 16);
    }

    short8v ev[TOPK], rv[TOPK];
    #pragma unroll
    for (int k = 0; k < TOPK; ++k)
        ev[k] = *(const short8v*)(emb_bf + (size_t)skA[k] * 256 + el * 8);
    #pragma unroll
    for (int k = 0; k < TOPK; ++k)
        rv[k] = *(const short8v*)(rel_bf + (size_t)rkA[k] * 256 + el * 8);
    asm volatile("s_waitcnt vmcnt(0)" ::: "memory");

    const float rsh = 1.f / sumsS[nib][h];
    float acc[8] = {0.f, 0.f, 0.f, 0.f, 0.f, 0.f, 0.f, 0.f};
    #pragma unroll
    for (int k = 0; k < TOPK; ++k) {
        float w = wtsS[nib][k][h] * rsh;
        #pragma unroll
        for (int j = 0; j < 8; ++j)
            acc[j] += w * (bf2f((unsigned short)ev[k][j]) + bf2f((unsigned short)rv[k][j]));
    }

    short8v ov;
    #pragma unroll
    for (int j = 0; j < 8; ++j) ov[j] = (short)bf16_rne(acc[j]);
    *(short8v*)(napk + (size_t)n * 256 + el * 8) = ov;   // row-major: coalesced
}

// ---------------- K4: MFMA GEMM, row-major A staged to LDS, B hi packed, f32 tanh out ----------------
__global__ __launch_bounds__(256, 4) void gemm_out(
    const unsigned short* __restrict__ A, const unsigned short* __restrict__ Bpkh,
    float* __restrict__ Cout, int M)
{
    __shared__ unsigned short As[64][264];

    const int tid = threadIdx.x;
    const int l = tid & 63;
    const int w = tid >> 6;
    const int bm = blockIdx.x * 64;
    const int rl = l & 15;
    const int ql = l >> 4;

    const unsigned short* Ag = A + (size_t)bm * 256;
    #pragma unroll
    for (int i = 0; i < 8; ++i) {
        int u = i * 256 + tid;
        short8v v = *(const short8v*)(Ag + (size_t)u * 8);
        *(short8v*)&As[u >> 5][(u & 31) * 8] = v;
    }
    __syncthreads();

    const unsigned short* bhb = Bpkh + (size_t)w * 16384 + l * 8;

    f32x4 acc[4][4];
    #pragma unroll
    for (int i = 0; i < 4; ++i)
        #pragma unroll
        for (int j = 0; j < 4; ++j) acc[i][j] = (f32x4){0.f, 0.f, 0.f, 0.f};

    #pragma unroll
    for (int ks = 0; ks < 8; ++ks) {
        short8v ah[4], bh[4];
        #pragma unroll
        for (int mf = 0; mf < 4; ++mf)
            ah[mf] = *(const short8v*)&As[mf * 16 + rl][ks * 32 + ql * 8];
        #pragma unroll
        for (int nf = 0; nf < 4; ++nf)
            bh[nf] = *(const short8v*)(bhb + nf * 4096 + ks * 512);
        #pragma unroll
        for (int mf = 0; mf < 4; ++mf)
            #pragma unroll
            for (int nf = 0; nf < 4; ++nf)
                acc[mf][nf] = __builtin_amdgcn_mfma_f32_16x16x32_bf16(ah[mf], bh[nf], acc[mf][nf], 0, 0, 0);
    }

    #pragma unroll
    for (int mf = 0; mf < 4; ++mf) {
        int row0 = bm + mf * 16 + ql * 4;
        #pragma unroll
        for (int nf = 0; nf < 4; ++nf) {
            int c = w * 64 + nf * 16 + rl;
            #pragma unroll
            for (int j = 0; j < 4; ++j) {
                int r = row0 + j;
                if (r < M) {
                    float v = acc[mf][nf][j];
                    Cout[(size_t)r * 256 + c] = 1.f - 2.f / (__expf(2.f * v) + 1.f);
                }
            }
        }
    }
}

extern "C" void kernel_launch(void* const* d_in, const int* in_sizes, int n_in,
                              void* d_out, int out_size, void* d_ws, size_t ws_size,
                              hipStream_t stream) {
    const float* ent  = (const float*)d_in[0];
    const float* rel  = (const float*)d_in[1];
    const float* W    = (const float*)d_in[2];
    const float* W_r  = (const float*)d_in[3];
    const float* a    = (const float*)d_in[4];
    const float* nw   = (const float*)d_in[5];
    const int*   srcp = (const int*)d_in[6];
    const int*   ridp = (const int*)d_in[7];
    float* out = (float*)d_out;

    if (ws_size < WS_NEED) return;

    char* ws = (char*)d_ws;
    double* ssrc0 = (double*)(ws + OFF_SSRC0);
    double* sr0   = (double*)(ws + OFF_SR0);
    double* u0    = (double*)(ws + OFF_U0);
    double* v0    = (double*)(ws + OFF_V0);
    float*  SS    = (float*)(ws + OFF_SS);
    float*  SSR   = (float*)(ws + OFF_SSR);
    float*  U8    = (float*)(ws + OFF_U8);
    float*  V8    = (float*)(ws + OFF_V8);
    unsigned short* b1h = (unsigned short*)(ws + OFF_B1H);
    unsigned short* b2h = (unsigned short*)(ws + OFF_B2H);
    unsigned short* b3h = (unsigned short*)(ws + OFF_B3H);
    unsigned short* rpk = (unsigned short*)(ws + OFF_RPK);
    unsigned short* apk = (unsigned short*)(ws + OFF_EAH);
    unsigned short* embbf = (unsigned short*)(ws + OFF_EMBBF);
    unsigned short* relbf = (unsigned short*)(ws + OFF_RELBF);
    unsigned short* napk = apk;   // neigh row-major aliases ent row-major (dead after gemm_hi)

    setup_kernel<<<258, 256, 0, stream>>>(W, W_r, a, nw, U8, u0, V8, v0,
                                          b1h, b2h, b3h);
    ss_kernel<<<2111, 256, 0, stream>>>(ent, rel, U8, u0, V8, v0,
                                        SS, ssrc0, apk, SSR, sr0, rpk);
    gemm_hi<<<790, 256, 0, stream>>>(apk, b1h, embbf, N_ENT, 782,
                                     rpk, b3h, relbf, N_REL);
    node_kernel<<<6250, 256, 0, stream>>>(srcp, ridp, SS, ssrc0, SSR, sr0,
                                          embbf, relbf, napk);
    gemm_out<<<782, 256, 0, stream>>>(napk, b2h, out, N_ENT);
}